// Round 2
// baseline (305.482 us; speedup 1.0000x reference)
//
#include <hip/hip_runtime.h>
#include <hip/hip_bf16.h>

#define QMAX 255.0f

// ws float-offset layout
#define OFF_QW1 16
#define OFF_QW2 466       // 16+450
#define OFF_QW3 2866      // +2400
#define OFF_QW4 50866     // +48000
#define OFF_QW5 60946     // +10080
#define OFF_H1  61952     // aligned
#define OFF_H2  (OFF_H1 + 4096*6*14*14)
#define OFF_H3  (OFF_H2 + 4096*16*5*5)
#define OFF_H4  (OFF_H3 + 4096*120)

__device__ __forceinline__ float get_scale(const unsigned* slots, int i) {
    float amax = __uint_as_float(slots[i]);
    float s = amax / QMAX;
    if (!(s > 0.0f)) s = 1.0f;
    return s;
}

// block-wide max reduce; result valid on tid 0. red must hold >=4 floats.
__device__ __forceinline__ float block_max(float v, float* red) {
    #pragma unroll
    for (int off = 32; off > 0; off >>= 1) v = fmaxf(v, __shfl_xor(v, off));
    int wid = threadIdx.x >> 6;
    if ((threadIdx.x & 63) == 0) red[wid] = v;
    __syncthreads();
    return fmaxf(fmaxf(red[0], red[1]), fmaxf(red[2], red[3]));
}

// ---------------- weight prep: per-weight absmax + quantize (5 blocks) ----------------
__global__ __launch_bounds__(256) void k_prep_w(
    const float* __restrict__ w1, const float* __restrict__ w2,
    const float* __restrict__ w3, const float* __restrict__ w4,
    const float* __restrict__ w5,
    unsigned* __restrict__ slots,
    float* __restrict__ qw1, float* __restrict__ qw2, float* __restrict__ qw3,
    float* __restrict__ qw4, float* __restrict__ qw5)
{
    __shared__ float red[4];
    int b = blockIdx.x, tid = threadIdx.x;
    if (b == 0 && tid < 5) slots[tid] = 0u;   // init activation absmax slots 0..4
    const float* w; float* q; int n;
    if      (b == 0) { w = w1; q = qw1; n = 450;   }
    else if (b == 1) { w = w2; q = qw2; n = 2400;  }
    else if (b == 2) { w = w3; q = qw3; n = 48000; }
    else if (b == 3) { w = w4; q = qw4; n = 10080; }
    else             { w = w5; q = qw5; n = 840;   }
    float m = 0.0f;
    for (int i = tid; i < n; i += 256) m = fmaxf(m, fabsf(w[i]));
    float amax = block_max(m, red);
    if (tid == 0) slots[5 + b] = __float_as_uint(amax);
    float s = amax / QMAX; if (!(s > 0.0f)) s = 1.0f;
    for (int i = tid; i < n; i += 256) q[i] = rintf(w[i] / s);
}

// ---------------- absmax over x ----------------
__global__ __launch_bounds__(256) void k_absmax_x(
    const float4* __restrict__ x, int n4, unsigned* __restrict__ slot)
{
    __shared__ float red[4];
    int tid = threadIdx.x;
    float m = 0.0f;
    for (int i = blockIdx.x * blockDim.x + tid; i < n4; i += gridDim.x * blockDim.x) {
        float4 v = x[i];
        m = fmaxf(m, fmaxf(fmaxf(fabsf(v.x), fabsf(v.y)), fmaxf(fabsf(v.z), fabsf(v.w))));
    }
    m = block_max(m, red);
    if (tid == 0) atomicMax(slot, __float_as_uint(m));
}

// ---------------- conv1 + relu + pool: [B,3,32,32] -> [B,6,14,14] ----------------
// xs padded [3][32][34]; weights in LDS as wl[c][oc][26]
__global__ __launch_bounds__(256, 4) void k_conv1(
    const float* __restrict__ x, const float* __restrict__ qw1,
    const unsigned* __restrict__ slots, unsigned* __restrict__ slot_out,
    float* __restrict__ h1)
{
    __shared__ float xs[3 * 32 * 34];
    __shared__ float wl[3 * 6 * 26];
    __shared__ float red[4];
    int b = blockIdx.x, tid = threadIdx.x;
    float sx = get_scale(slots, 0);
    const float* xb = x + (long)b * 3072;
    for (int i = tid; i < 3072; i += 256) {
        int c = i >> 10, rem = i & 1023, y = rem >> 5, xc = rem & 31;
        xs[c * 1088 + y * 34 + xc] = rintf(xb[i] / sx);
    }
    // weights: qw1 is [oc][c][5][5]; reorder to wl[c][oc][k]
    for (int i = tid; i < 450; i += 256) {
        int oc = i / 75, rem = i % 75, c = rem / 25, k = rem % 25;
        wl[c * 156 + oc * 26 + k] = qw1[i];
    }
    __syncthreads();
    float mscale = sx * get_scale(slots, 5);

    float vmax = 0.0f;
    if (tid < 196) {
        int py = tid / 14, px = tid % 14;
        int x0 = 2 * px, y0 = 2 * py;
        float acc[6][4];
        #pragma unroll
        for (int oc = 0; oc < 6; oc++)
            #pragma unroll
            for (int p = 0; p < 4; p++) acc[oc][p] = 0.0f;

        for (int c = 0; c < 3; c++) {
            int base = c * 1088 + y0 * 34 + x0;   // even -> 8B aligned
            float xw[6][6];
            #pragma unroll
            for (int r = 0; r < 6; r++) {
                const float2* row = (const float2*)&xs[base + r * 34];
                #pragma unroll
                for (int h = 0; h < 3; h++) {
                    float2 v = row[h];
                    xw[r][2 * h] = v.x; xw[r][2 * h + 1] = v.y;
                }
            }
            #pragma unroll
            for (int oc = 0; oc < 6; oc++) {
                int wbase = c * 156 + oc * 26;
                #pragma unroll
                for (int ky = 0; ky < 5; ky++)
                    #pragma unroll
                    for (int kx = 0; kx < 5; kx++) {
                        float w = wl[wbase + ky * 5 + kx];
                        acc[oc][0] += xw[ky][kx]     * w;
                        acc[oc][1] += xw[ky][kx + 1] * w;
                        acc[oc][2] += xw[ky + 1][kx] * w;
                        acc[oc][3] += xw[ky + 1][kx + 1] * w;
                    }
            }
        }
        #pragma unroll
        for (int oc = 0; oc < 6; oc++) {
            float m = fmaxf(fmaxf(acc[oc][0], acc[oc][1]), fmaxf(acc[oc][2], acc[oc][3]));
            float v = fmaxf(m * mscale, 0.0f);
            h1[((long)b * 6 + oc) * 196 + tid] = v;
            vmax = fmaxf(vmax, v);
        }
    }
    vmax = block_max(vmax, red);
    if (tid == 0) atomicMax(slot_out, __float_as_uint(vmax));
}

// ---------------- conv2 + relu + pool: [B,6,14,14] -> [B,16,5,5] (8 img/block) ----------------
// weights in LDS as wl[c][oc][26]
__global__ __launch_bounds__(256, 4) void k_conv2(
    const float* __restrict__ h1, const float* __restrict__ qw2,
    const unsigned* __restrict__ slots, unsigned* __restrict__ slot_out,
    float* __restrict__ h2)
{
    __shared__ float xs[8 * 6 * 196];
    __shared__ float wl[6 * 16 * 26];
    __shared__ float red[4];
    int b0 = blockIdx.x * 8, tid = threadIdx.x;
    float s1 = get_scale(slots, 1);
    const float* src = h1 + (long)b0 * 1176;
    for (int i = tid; i < 8 * 1176; i += 256) xs[i] = rintf(src[i] / s1);
    // qw2 is [oc=16][c=6][5][5]; reorder to wl[c][oc][k]
    for (int i = tid; i < 2400; i += 256) {
        int oc = i / 150, rem = i % 150, c = rem / 25, k = rem % 25;
        wl[c * 416 + oc * 26 + k] = qw2[i];
    }
    __syncthreads();
    float mscale = s1 * get_scale(slots, 6);

    float vmax = 0.0f;
    if (tid < 200) {
        int img = tid / 25, p = tid % 25;
        int py = p / 5, px = p % 5;
        int xbase = img * 1176;
        for (int ocg = 0; ocg < 2; ocg++) {
            float acc[8][4];
            #pragma unroll
            for (int oc = 0; oc < 8; oc++)
                #pragma unroll
                for (int q = 0; q < 4; q++) acc[oc][q] = 0.0f;

            for (int c = 0; c < 6; c++) {
                int base = xbase + c * 196 + 2 * py * 14 + 2 * px;  // even -> 8B aligned
                float xw[6][6];
                #pragma unroll
                for (int r = 0; r < 6; r++) {
                    const float2* row = (const float2*)&xs[base + r * 14];
                    #pragma unroll
                    for (int h = 0; h < 3; h++) {
                        float2 v = row[h];
                        xw[r][2 * h] = v.x; xw[r][2 * h + 1] = v.y;
                    }
                }
                #pragma unroll
                for (int oc = 0; oc < 8; oc++) {
                    int wbase = c * 416 + (ocg * 8 + oc) * 26;
                    #pragma unroll
                    for (int ky = 0; ky < 5; ky++)
                        #pragma unroll
                        for (int kx = 0; kx < 5; kx++) {
                            float w = wl[wbase + ky * 5 + kx];
                            acc[oc][0] += xw[ky][kx]     * w;
                            acc[oc][1] += xw[ky][kx + 1] * w;
                            acc[oc][2] += xw[ky + 1][kx] * w;
                            acc[oc][3] += xw[ky + 1][kx + 1] * w;
                        }
                }
            }
            #pragma unroll
            for (int oc = 0; oc < 8; oc++) {
                float m = fmaxf(fmaxf(acc[oc][0], acc[oc][1]), fmaxf(acc[oc][2], acc[oc][3]));
                float v = fmaxf(m * mscale, 0.0f);
                h2[((long)(b0 + img) * 16 + ocg * 8 + oc) * 25 + p] = v;
                vmax = fmaxf(vmax, v);
            }
        }
    }
    vmax = block_max(vmax, red);
    if (tid == 0) atomicMax(slot_out, __float_as_uint(vmax));
}

// ---------------- conv3 + relu: [B,16,5,5] -> [B,120]  (GEMM M=B,N=120,K=400; 16 img/block) ----------------
__global__ __launch_bounds__(256) void k_conv3(
    const float* __restrict__ h2, const float* __restrict__ qw3,
    const unsigned* __restrict__ slots, unsigned* __restrict__ slot_out,
    float* __restrict__ h3)
{
    __shared__ float xs[16 * 401];
    __shared__ float wt[50 * 120];
    __shared__ float red[4];
    int b0 = blockIdx.x * 16, tid = threadIdx.x;
    float s2 = get_scale(slots, 2);
    const float* src = h2 + (long)b0 * 400;
    for (int i = tid; i < 6400; i += 256) {
        int img = i / 400, k = i % 400;
        xs[img * 401 + k] = rintf(src[i] / s2);
    }
    float mscale = s2 * get_scale(slots, 7);
    int img = tid & 15, ocg = tid >> 4;
    int ocb = ocg * 8;
    float acc[8];
    #pragma unroll
    for (int j = 0; j < 8; j++) acc[j] = 0.0f;

    for (int cc = 0; cc < 8; cc++) {
        __syncthreads();
        for (int i = tid; i < 6000; i += 256) {
            int oc = i / 50, kk = i % 50;
            wt[kk * 120 + oc] = qw3[oc * 400 + cc * 50 + kk];
        }
        __syncthreads();
        if (ocg < 15) {
            for (int kk = 0; kk < 50; kk++) {
                float xv = xs[img * 401 + cc * 50 + kk];
                const float* wr = &wt[kk * 120 + ocb];
                #pragma unroll
                for (int j = 0; j < 8; j++) acc[j] += xv * wr[j];
            }
        }
    }
    float vmax = 0.0f;
    if (ocg < 15) {
        #pragma unroll
        for (int j = 0; j < 8; j++) {
            float v = fmaxf(acc[j] * mscale, 0.0f);
            h3[(long)(b0 + img) * 120 + ocb + j] = v;
            vmax = fmaxf(vmax, v);
        }
    }
    __syncthreads();
    vmax = block_max(vmax, red);
    if (tid == 0) atomicMax(slot_out, __float_as_uint(vmax));
}

// ---------------- fc4 + relu: [B,120] x [84,120] -> [B,84]  (16 img/block) ----------------
__global__ __launch_bounds__(256) void k_fc4(
    const float* __restrict__ h3, const float* __restrict__ qw4,
    const unsigned* __restrict__ slots, unsigned* __restrict__ slot_out,
    float* __restrict__ h4)
{
    __shared__ float xs[16 * 121];
    __shared__ float wt[120 * 84];
    __shared__ float red[4];
    int b0 = blockIdx.x * 16, tid = threadIdx.x;
    float s3 = get_scale(slots, 3);
    const float* src = h3 + (long)b0 * 120;
    for (int i = tid; i < 1920; i += 256) {
        int img = i / 120, k = i % 120;
        xs[img * 121 + k] = rintf(src[i] / s3);
    }
    for (int i = tid; i < 10080; i += 256) {
        int oc = i / 120, k = i % 120;
        wt[k * 84 + oc] = qw4[i];
    }
    __syncthreads();
    float mscale = s3 * get_scale(slots, 8);
    int img = tid & 15, ocg = tid >> 4;
    int ocb = ocg * 6;
    float vmax = 0.0f;
    if (ocg < 14) {
        float acc[6];
        #pragma unroll
        for (int j = 0; j < 6; j++) acc[j] = 0.0f;
        for (int k = 0; k < 120; k++) {
            float xv = xs[img * 121 + k];
            const float* wr = &wt[k * 84 + ocb];
            #pragma unroll
            for (int j = 0; j < 6; j++) acc[j] += xv * wr[j];
        }
        #pragma unroll
        for (int j = 0; j < 6; j++) {
            float v = fmaxf(acc[j] * mscale, 0.0f);
            h4[(long)(b0 + img) * 84 + ocb + j] = v;
            vmax = fmaxf(vmax, v);
        }
    }
    vmax = block_max(vmax, red);
    if (tid == 0) atomicMax(slot_out, __float_as_uint(vmax));
}

// ---------------- fc5: [B,84] x [10,84] -> out [B,10] ----------------
__global__ __launch_bounds__(256) void k_fc5(
    const float* __restrict__ h4, const float* __restrict__ qw5,
    const unsigned* __restrict__ slots, float* __restrict__ out)
{
    __shared__ float wt[840];
    int tid = threadIdx.x;
    int gid = blockIdx.x * 256 + tid;
    float s4 = get_scale(slots, 4);
    for (int i = tid; i < 840; i += 256) wt[i] = qw5[i];
    __syncthreads();
    float mscale = s4 * get_scale(slots, 9);
    int img = gid / 10, oc = gid % 10;
    if (img < 4096) {
        float acc = 0.0f;
        const float* xr = h4 + (long)img * 84;
        const float* wr = &wt[oc * 84];
        for (int k = 0; k < 84; k++) acc += rintf(xr[k] / s4) * wr[k];
        out[gid] = acc * mscale;
    }
}

extern "C" void kernel_launch(void* const* d_in, const int* in_sizes, int n_in,
                              void* d_out, int out_size, void* d_ws, size_t ws_size,
                              hipStream_t stream) {
    const float* x  = (const float*)d_in[0];
    const float* w1 = (const float*)d_in[1];
    const float* w2 = (const float*)d_in[2];
    const float* w3 = (const float*)d_in[3];
    const float* w4 = (const float*)d_in[4];
    const float* w5 = (const float*)d_in[5];
    float* out = (float*)d_out;
    float* ws = (float*)d_ws;
    unsigned* slots = (unsigned*)d_ws;
    float* qw1 = ws + OFF_QW1;
    float* qw2 = ws + OFF_QW2;
    float* qw3 = ws + OFF_QW3;
    float* qw4 = ws + OFF_QW4;
    float* qw5 = ws + OFF_QW5;
    float* h1 = ws + OFF_H1;
    float* h2 = ws + OFF_H2;
    float* h3 = ws + OFF_H3;
    float* h4 = ws + OFF_H4;

    k_prep_w<<<5, 256, 0, stream>>>(w1, w2, w3, w4, w5, slots, qw1, qw2, qw3, qw4, qw5);
    k_absmax_x<<<2048, 256, 0, stream>>>((const float4*)x, 4096 * 3 * 32 * 32 / 4, slots + 0);
    k_conv1<<<4096, 256, 0, stream>>>(x, qw1, slots, slots + 1, h1);
    k_conv2<<<512, 256, 0, stream>>>(h1, qw2, slots, slots + 2, h2);
    k_conv3<<<256, 256, 0, stream>>>(h2, qw3, slots, slots + 3, h3);
    k_fc4<<<256, 256, 0, stream>>>(h3, qw4, slots, slots + 4, h4);
    k_fc5<<<160, 256, 0, stream>>>(h4, qw5, slots, out);
}

// Round 3
// 262.176 us; speedup vs baseline: 1.1652x; 1.1652x over previous
//
#include <hip/hip_runtime.h>
#include <hip/hip_bf16.h>

#define QMAX 255.0f

// ws float-offset layout
#define OFF_QW1 16
#define OFF_QW2 466       // 16+450
#define OFF_QW3 2866      // +2400
#define OFF_QW4 50866     // +48000
#define OFF_QW5 60946     // +10080
#define OFF_H1  61952     // aligned
#define OFF_H2  (OFF_H1 + 4096*6*14*14)
#define OFF_H3  (OFF_H2 + 4096*16*5*5)
#define OFF_H4  (OFF_H3 + 4096*120)

__device__ __forceinline__ float get_scale(const unsigned* slots, int i) {
    float amax = __uint_as_float(slots[i]);
    float s = amax / QMAX;
    if (!(s > 0.0f)) s = 1.0f;
    return s;
}

// block-wide max reduce for 256-thread blocks; red must hold >=4 floats.
__device__ __forceinline__ float block_max256(float v, float* red) {
    #pragma unroll
    for (int off = 32; off > 0; off >>= 1) v = fmaxf(v, __shfl_xor(v, off));
    if ((threadIdx.x & 63) == 0) red[threadIdx.x >> 6] = v;
    __syncthreads();
    return fmaxf(fmaxf(red[0], red[1]), fmaxf(red[2], red[3]));
}

// bf16 pack/unpack: quantized values are exact integers |q|<=255 -> bf16 exact.
__device__ __forceinline__ float bflo(unsigned u) { return __uint_as_float(u << 16); }
__device__ __forceinline__ float bfhi(unsigned u) { return __uint_as_float(u & 0xffff0000u); }
__device__ __forceinline__ unsigned f2bf(float f) { return __float_as_uint(f) >> 16; }

// ---------------- weight prep: per-weight absmax + quantize (5 blocks) ----------------
__global__ __launch_bounds__(256) void k_prep_w(
    const float* __restrict__ w1, const float* __restrict__ w2,
    const float* __restrict__ w3, const float* __restrict__ w4,
    const float* __restrict__ w5,
    unsigned* __restrict__ slots,
    float* __restrict__ qw1, float* __restrict__ qw2, float* __restrict__ qw3,
    float* __restrict__ qw4, float* __restrict__ qw5)
{
    __shared__ float red[4];
    int b = blockIdx.x, tid = threadIdx.x;
    if (b == 0 && tid < 5) slots[tid] = 0u;   // init activation absmax slots 0..4
    const float* w; float* q; int n;
    if      (b == 0) { w = w1; q = qw1; n = 450;   }
    else if (b == 1) { w = w2; q = qw2; n = 2400;  }
    else if (b == 2) { w = w3; q = qw3; n = 48000; }
    else if (b == 3) { w = w4; q = qw4; n = 10080; }
    else             { w = w5; q = qw5; n = 840;   }
    float m = 0.0f;
    for (int i = tid; i < n; i += 256) m = fmaxf(m, fabsf(w[i]));
    float amax = block_max256(m, red);
    if (tid == 0) slots[5 + b] = __float_as_uint(amax);
    float s = amax / QMAX; if (!(s > 0.0f)) s = 1.0f;
    for (int i = tid; i < n; i += 256) q[i] = rintf(w[i] / s);
}

// ---------------- absmax over x ----------------
__global__ __launch_bounds__(256) void k_absmax_x(
    const float4* __restrict__ x, int n4, unsigned* __restrict__ slot)
{
    __shared__ float red[4];
    int tid = threadIdx.x;
    float m = 0.0f;
    for (int i = blockIdx.x * blockDim.x + tid; i < n4; i += gridDim.x * blockDim.x) {
        float4 v = x[i];
        m = fmaxf(m, fmaxf(fmaxf(fabsf(v.x), fabsf(v.y)), fmaxf(fabsf(v.z), fabsf(v.w))));
    }
    m = block_max256(m, red);
    if (tid == 0) atomicMax(slot, __float_as_uint(m));
}

// ---------------- conv1 + relu + pool: [B,3,32,32] -> [B,6,14,14] ----------------
// 5 img/block; thread = (img, 2x2 pool block). xs bf16 [img][3][32][36].
__global__ __launch_bounds__(256, 3) void k_conv1(
    const float* __restrict__ x, const float* __restrict__ qw1,
    const unsigned* __restrict__ slots, unsigned* __restrict__ slot_out,
    float* __restrict__ h1)
{
    __shared__ unsigned short xs[5 * 3456];   // bf16, [img][c][y][36]
    __shared__ float wl[6 * 3 * 28];          // [oc][c][28] (25 used)
    __shared__ float red[4];
    int b0 = blockIdx.x * 5, tid = threadIdx.x;
    int nimg = min(5, 4096 - b0);
    float sx = get_scale(slots, 0);
    // stage quantized x as bf16 (exact integers), paired writes
    for (int i = tid; i < nimg * 1536; i += 256) {
        int img = i / 1536, r = i % 1536;       // r = pair index
        int c = r >> 9, rem = r & 511, y = rem >> 4, xc = (rem & 15) * 2;
        const float* src = x + (long)(b0 + img) * 3072 + c * 1024 + y * 32 + xc;
        float q0 = rintf(src[0] / sx), q1 = rintf(src[1] / sx);
        unsigned pk = f2bf(q0) | (f2bf(q1) << 16);
        *(unsigned*)&xs[img * 3456 + c * 1152 + y * 36 + xc] = pk;
    }
    for (int i = tid; i < 450; i += 256) {
        int oc = i / 75, rem = i % 75, c = rem / 25, k = rem % 25;
        wl[(oc * 3 + c) * 28 + k] = qw1[i];
    }
    __syncthreads();
    float mscale = sx * get_scale(slots, 5);

    float vmax = 0.0f;
    int img = tid / 49, t = tid % 49;
    if (img < nimg) {
        int pb = t / 7, qb = t % 7;
        int base0 = img * 3456 + pb * 144 + qb * 4;   // rows 4pb.., cols 4qb..
        #pragma unroll
        for (int ocg = 0; ocg < 2; ocg++) {
            float acc[3][16];
            #pragma unroll
            for (int o = 0; o < 3; o++)
                #pragma unroll
                for (int p = 0; p < 16; p++) acc[o][p] = 0.0f;
            #pragma unroll 1
            for (int c = 0; c < 3; c++) {
                float win[8][8];
                #pragma unroll
                for (int r = 0; r < 8; r++) {
                    const uint2* p = (const uint2*)&xs[base0 + c * 1152 + r * 36];
                    uint2 a = p[0], b = p[1];
                    win[r][0] = bflo(a.x); win[r][1] = bfhi(a.x);
                    win[r][2] = bflo(a.y); win[r][3] = bfhi(a.y);
                    win[r][4] = bflo(b.x); win[r][5] = bfhi(b.x);
                    win[r][6] = bflo(b.y); win[r][7] = bfhi(b.y);
                }
                #pragma unroll
                for (int o = 0; o < 3; o++) {
                    const float4* wp = (const float4*)&wl[((ocg * 3 + o) * 3 + c) * 28];
                    float w[28];
                    #pragma unroll
                    for (int q = 0; q < 7; q++) {
                        float4 wv = wp[q];
                        w[q*4+0] = wv.x; w[q*4+1] = wv.y; w[q*4+2] = wv.z; w[q*4+3] = wv.w;
                    }
                    #pragma unroll
                    for (int ky = 0; ky < 5; ky++)
                        #pragma unroll
                        for (int kx = 0; kx < 5; kx++) {
                            float wv = w[ky * 5 + kx];
                            #pragma unroll
                            for (int i2 = 0; i2 < 4; i2++)
                                #pragma unroll
                                for (int j = 0; j < 4; j++)
                                    acc[o][i2 * 4 + j] += win[i2 + ky][j + kx] * wv;
                        }
                }
            }
            #pragma unroll
            for (int o = 0; o < 3; o++) {
                int oc = ocg * 3 + o;
                float* dst = h1 + ((long)(b0 + img) * 6 + oc) * 196;
                #pragma unroll
                for (int pi = 0; pi < 2; pi++)
                    #pragma unroll
                    for (int pj = 0; pj < 2; pj++) {
                        float m = fmaxf(fmaxf(acc[o][(2*pi)*4 + 2*pj],     acc[o][(2*pi)*4 + 2*pj+1]),
                                        fmaxf(acc[o][(2*pi+1)*4 + 2*pj],   acc[o][(2*pi+1)*4 + 2*pj+1]));
                        float v = fmaxf(m * mscale, 0.0f);
                        dst[(2*pb + pi) * 14 + (2*qb + pj)] = v;
                        vmax = fmaxf(vmax, v);
                    }
            }
        }
    }
    vmax = block_max256(vmax, red);
    if (tid == 0) atomicMax(slot_out, __float_as_uint(vmax));
}

// ---------------- conv2 + relu + pool: [B,6,14,14] -> [B,16,5,5] ----------------
// 8 img/block; thread = (img, oc, pr-group): g0 handles pool rows 0-2, g1 rows 3-4.
__global__ __launch_bounds__(256, 3) void k_conv2(
    const float* __restrict__ h1, const float* __restrict__ qw2,
    const unsigned* __restrict__ slots, unsigned* __restrict__ slot_out,
    float* __restrict__ h2)
{
    __shared__ float xs[8 * 1176];    // [img][c][196]
    __shared__ float wl[16 * 172];    // [oc] stride 172; [c][28] inside
    __shared__ float red[4];
    int b0 = blockIdx.x * 8, tid = threadIdx.x;
    float s1 = get_scale(slots, 1);
    const float* src = h1 + (long)b0 * 1176;
    for (int i = tid; i < 9408; i += 256) xs[i] = rintf(src[i] / s1);
    for (int i = tid; i < 2400; i += 256) {
        int oc = i / 150, rem = i % 150, c = rem / 25, k = rem % 25;
        wl[oc * 172 + c * 28 + k] = qw2[i];
    }
    __syncthreads();
    float mscale = s1 * get_scale(slots, 6);

    int oc = tid & 15, img = (tid >> 4) & 7, g = tid >> 7;
    int xb = img * 1176;
    const float4* wp = (const float4*)&wl[oc * 172];
    float* dst = h2 + ((long)(b0 + img) * 16 + oc) * 25;
    float vmax = 0.0f;
    int prlo = g * 3, prhi = g ? 5 : 3;
    for (int pr = prlo; pr < prhi; pr++) {
        float acc[2][10];
        #pragma unroll
        for (int cr = 0; cr < 2; cr++)
            #pragma unroll
            for (int cc = 0; cc < 10; cc++) acc[cr][cc] = 0.0f;
        #pragma unroll 1
        for (int c = 0; c < 6; c++) {
            float win[6][14];
            #pragma unroll
            for (int r = 0; r < 6; r++) {
                const float2* p = (const float2*)&xs[xb + c * 196 + (2 * pr + r) * 14];
                #pragma unroll
                for (int h = 0; h < 7; h++) {
                    float2 v = p[h];
                    win[r][2*h] = v.x; win[r][2*h+1] = v.y;
                }
            }
            float w[28];
            const float4* wc = wp + c * 7;
            #pragma unroll
            for (int q = 0; q < 7; q++) {
                float4 wv = wc[q];
                w[q*4+0] = wv.x; w[q*4+1] = wv.y; w[q*4+2] = wv.z; w[q*4+3] = wv.w;
            }
            #pragma unroll
            for (int ky = 0; ky < 5; ky++)
                #pragma unroll
                for (int kx = 0; kx < 5; kx++) {
                    float wv = w[ky * 5 + kx];
                    #pragma unroll
                    for (int cr = 0; cr < 2; cr++)
                        #pragma unroll
                        for (int cc = 0; cc < 10; cc++)
                            acc[cr][cc] += win[cr + ky][cc + kx] * wv;
                }
        }
        #pragma unroll
        for (int pc = 0; pc < 5; pc++) {
            float m = fmaxf(fmaxf(acc[0][2*pc], acc[0][2*pc+1]),
                            fmaxf(acc[1][2*pc], acc[1][2*pc+1]));
            float v = fmaxf(m * mscale, 0.0f);
            dst[pr * 5 + pc] = v;
            vmax = fmaxf(vmax, v);
        }
    }
    vmax = block_max256(vmax, red);
    if (tid == 0) atomicMax(slot_out, __float_as_uint(vmax));
}

// ---------------- conv3 + relu: [B,16,5,5] -> [B,120]  (16 img/block) ----------------
__global__ __launch_bounds__(256) void k_conv3(
    const float* __restrict__ h2, const float* __restrict__ qw3,
    const unsigned* __restrict__ slots, unsigned* __restrict__ slot_out,
    float* __restrict__ h3)
{
    __shared__ float xs[16 * 401];
    __shared__ float wt[50 * 121];   // padded: kk stride 121 kills staging write conflicts
    __shared__ float red[4];
    int b0 = blockIdx.x * 16, tid = threadIdx.x;
    float s2 = get_scale(slots, 2);
    const float* src = h2 + (long)b0 * 400;
    for (int i = tid; i < 6400; i += 256) {
        int img = i / 400, k = i % 400;
        xs[img * 401 + k] = rintf(src[i] / s2);
    }
    float mscale = s2 * get_scale(slots, 7);
    int img = tid & 15, ocg = tid >> 4;
    int ocb = ocg * 8;
    float acc[8];
    #pragma unroll
    for (int j = 0; j < 8; j++) acc[j] = 0.0f;

    for (int cc = 0; cc < 8; cc++) {
        __syncthreads();
        for (int i = tid; i < 6000; i += 256) {
            int oc = i / 50, kk = i % 50;
            wt[kk * 121 + oc] = qw3[oc * 400 + cc * 50 + kk];
        }
        __syncthreads();
        if (ocg < 15) {
            for (int kk = 0; kk < 50; kk++) {
                float xv = xs[img * 401 + cc * 50 + kk];
                const float* wr = &wt[kk * 121 + ocb];
                #pragma unroll
                for (int j = 0; j < 8; j++) acc[j] += xv * wr[j];
            }
        }
    }
    float vmax = 0.0f;
    if (ocg < 15) {
        #pragma unroll
        for (int j = 0; j < 8; j++) {
            float v = fmaxf(acc[j] * mscale, 0.0f);
            h3[(long)(b0 + img) * 120 + ocb + j] = v;
            vmax = fmaxf(vmax, v);
        }
    }
    __syncthreads();
    vmax = block_max256(vmax, red);
    if (tid == 0) atomicMax(slot_out, __float_as_uint(vmax));
}

// ---------------- fc4 + relu: [B,120] x [84,120] -> [B,84]  (16 img/block) ----------------
__global__ __launch_bounds__(256) void k_fc4(
    const float* __restrict__ h3, const float* __restrict__ qw4,
    const unsigned* __restrict__ slots, unsigned* __restrict__ slot_out,
    float* __restrict__ h4)
{
    __shared__ float xs[16 * 121];
    __shared__ float wt[120 * 85];   // padded stride 85
    __shared__ float red[4];
    int b0 = blockIdx.x * 16, tid = threadIdx.x;
    float s3 = get_scale(slots, 3);
    const float* src = h3 + (long)b0 * 120;
    for (int i = tid; i < 1920; i += 256) {
        int img = i / 120, k = i % 120;
        xs[img * 121 + k] = rintf(src[i] / s3);
    }
    for (int i = tid; i < 10080; i += 256) {
        int oc = i / 120, k = i % 120;
        wt[k * 85 + oc] = qw4[i];
    }
    __syncthreads();
    float mscale = s3 * get_scale(slots, 8);
    int img = tid & 15, ocg = tid >> 4;
    int ocb = ocg * 6;
    float vmax = 0.0f;
    if (ocg < 14) {
        float acc[6];
        #pragma unroll
        for (int j = 0; j < 6; j++) acc[j] = 0.0f;
        for (int k = 0; k < 120; k++) {
            float xv = xs[img * 121 + k];
            const float* wr = &wt[k * 85 + ocb];
            #pragma unroll
            for (int j = 0; j < 6; j++) acc[j] += xv * wr[j];
        }
        #pragma unroll
        for (int j = 0; j < 6; j++) {
            float v = fmaxf(acc[j] * mscale, 0.0f);
            h4[(long)(b0 + img) * 84 + ocb + j] = v;
            vmax = fmaxf(vmax, v);
        }
    }
    vmax = block_max256(vmax, red);
    if (tid == 0) atomicMax(slot_out, __float_as_uint(vmax));
}

// ---------------- fc5: [B,84] x [10,84] -> out [B,10] ----------------
__global__ __launch_bounds__(256) void k_fc5(
    const float* __restrict__ h4, const float* __restrict__ qw5,
    const unsigned* __restrict__ slots, float* __restrict__ out)
{
    __shared__ float wt[840];
    int tid = threadIdx.x;
    int gid = blockIdx.x * 256 + tid;
    float s4 = get_scale(slots, 4);
    for (int i = tid; i < 840; i += 256) wt[i] = qw5[i];
    __syncthreads();
    float mscale = s4 * get_scale(slots, 9);
    int img = gid / 10, oc = gid % 10;
    if (img < 4096) {
        float acc = 0.0f;
        const float* xr = h4 + (long)img * 84;
        const float* wr = &wt[oc * 84];
        for (int k = 0; k < 84; k++) acc += rintf(xr[k] / s4) * wr[k];
        out[gid] = acc * mscale;
    }
}

extern "C" void kernel_launch(void* const* d_in, const int* in_sizes, int n_in,
                              void* d_out, int out_size, void* d_ws, size_t ws_size,
                              hipStream_t stream) {
    const float* x  = (const float*)d_in[0];
    const float* w1 = (const float*)d_in[1];
    const float* w2 = (const float*)d_in[2];
    const float* w3 = (const float*)d_in[3];
    const float* w4 = (const float*)d_in[4];
    const float* w5 = (const float*)d_in[5];
    float* out = (float*)d_out;
    float* ws = (float*)d_ws;
    unsigned* slots = (unsigned*)d_ws;
    float* qw1 = ws + OFF_QW1;
    float* qw2 = ws + OFF_QW2;
    float* qw3 = ws + OFF_QW3;
    float* qw4 = ws + OFF_QW4;
    float* qw5 = ws + OFF_QW5;
    float* h1 = ws + OFF_H1;
    float* h2 = ws + OFF_H2;
    float* h3 = ws + OFF_H3;
    float* h4 = ws + OFF_H4;

    k_prep_w<<<5, 256, 0, stream>>>(w1, w2, w3, w4, w5, slots, qw1, qw2, qw3, qw4, qw5);
    k_absmax_x<<<2048, 256, 0, stream>>>((const float4*)x, 4096 * 3 * 32 * 32 / 4, slots + 0);
    k_conv1<<<820, 256, 0, stream>>>(x, qw1, slots, slots + 1, h1);
    k_conv2<<<512, 256, 0, stream>>>(h1, qw2, slots, slots + 2, h2);
    k_conv3<<<256, 256, 0, stream>>>(h2, qw3, slots, slots + 3, h3);
    k_fc4<<<256, 256, 0, stream>>>(h3, qw4, slots, slots + 4, h4);
    k_fc5<<<160, 256, 0, stream>>>(h4, qw5, slots, out);
}

// Round 4
// 152.178 us; speedup vs baseline: 2.0074x; 1.7228x over previous
//
#include <hip/hip_runtime.h>
#include <hip/hip_bf16.h>

#define QMAX 255.0f

typedef __attribute__((ext_vector_type(8))) short short8;
typedef __attribute__((ext_vector_type(4))) float f32x4;

// ws float offsets
#define OFF_QW5   16
#define OFF_BF1   856      // ushort[4096]   (2048 floats)
#define OFF_BF2   2904     // ushort[8192]   (4096 floats)
#define OFF_BF3   7000     // ushort[53248]  (26624 floats)
#define OFF_BF4   33624    // ushort[12288]  (6144 floats)
#define OFF_H1    40960
#define OFF_H2    4857856
#define OFF_H3    6496256
#define OFF_H4    6987776

#define IMG1 3076   // shorts per image in conv1 LDS (3072 + 4 pad -> 2-way-free banks)
#define IMG2 1348   // shorts per image in conv2 LDS (6*14*16 = 1344 + 4 pad)

__device__ __forceinline__ float get_scale(const unsigned* slots, int i) {
    float amax = __uint_as_float(slots[i]);
    float s = amax / QMAX;
    if (!(s > 0.0f)) s = 1.0f;
    return s;
}
__device__ __forceinline__ unsigned f2bf(float f) { return __float_as_uint(f) >> 16; } // exact for our ints

__device__ __forceinline__ float block_maxN(float v, float* red, int nw) {
    #pragma unroll
    for (int off = 32; off > 0; off >>= 1) v = fmaxf(v, __shfl_xor(v, off));
    if ((threadIdx.x & 63) == 0) red[threadIdx.x >> 6] = v;
    __syncthreads();
    float m = red[0];
    for (int i = 1; i < nw; i++) m = fmaxf(m, red[i]);
    return m;
}

// ---------------- absmax: x (blocks 0..2047) + all 5 weights (blocks 2048+) ----------------
__global__ __launch_bounds__(256) void k_absmax_all(
    const float4* __restrict__ x4,
    const float* __restrict__ w1, const float* __restrict__ w2,
    const float* __restrict__ w3, const float* __restrict__ w4,
    const float* __restrict__ w5, unsigned* __restrict__ slots)
{
    __shared__ float red[4];
    int b = blockIdx.x, tid = threadIdx.x;
    float m = 0.0f;
    int slot = -1;
    if (b < 2048) {
        slot = 0;
        for (int i = b * 256 + tid; i < 3145728; i += 2048 * 256) {
            float4 v = x4[i];
            m = fmaxf(m, fmaxf(fmaxf(fabsf(v.x), fabsf(v.y)), fmaxf(fabsf(v.z), fabsf(v.w))));
        }
    } else {
        int b2 = b - 2048;
        const float* w = nullptr; int n = 0, start = 0, stride = 256;
        if (b2 < 48)      { w = w3; n = 48000; start = b2 * 256;        stride = 48 * 256; slot = 7; }
        else if (b2 < 58) { w = w4; n = 10080; start = (b2 - 48) * 256; stride = 10 * 256; slot = 8; }
        else if (b2 == 58){ w = w2; n = 2400;  slot = 6; }
        else if (b2 == 59){ w = w1; n = 450;   slot = 5; }
        else if (b2 == 60){ w = w5; n = 840;   slot = 9; }
        if (slot >= 0)
            for (int i = start + tid; i < n; i += stride) m = fmaxf(m, fabsf(w[i]));
    }
    m = block_maxN(m, red, 4);
    if (tid == 0 && slot >= 0) atomicMax(&slots[slot], __float_as_uint(m));
}

// ---------------- build MFMA B-fragments (exact layout: col=lane&15, kchunk=lane>>4) ----------------
__global__ __launch_bounds__(256) void k_bfrag(
    const float* __restrict__ w1, const float* __restrict__ w2,
    const float* __restrict__ w3, const float* __restrict__ w4,
    const float* __restrict__ w5, const unsigned* __restrict__ slots,
    unsigned short* __restrict__ bf1, unsigned short* __restrict__ bf2,
    unsigned short* __restrict__ bf3, unsigned short* __restrict__ bf4,
    float* __restrict__ qw5)
{
    int idx = blockIdx.x * 256 + threadIdx.x;
    if (idx < 4096) {                     // conv1: [H2][S4][64][8], n=o*4+dx (o<3,dx<4)
        int f = idx, e = f & 7, l = (f >> 3) & 63, s = (f >> 9) & 3, H = f >> 11;
        int n = l & 15, g = l >> 4, C = 4 * s + g;
        float v = 0.f;
        if (n < 12 && C < 15) {
            int o = n >> 2, dx = n & 3, kx = e - dx;
            if (kx >= 0 && kx <= 4) {
                int c = C / 5, ky = C % 5, oc = 3 * H + o;
                v = rintf(w1[((oc * 3 + c) * 5 + ky) * 5 + kx] / get_scale(slots, 5));
            }
        }
        bf1[f] = (unsigned short)f2bf(v);
    } else if (idx < 12288) {             // conv2: [H2][S8][64][8], n=o*2+dx (o<8,dx<2)
        int f = idx - 4096, e = f & 7, l = (f >> 3) & 63, s = (f >> 9) & 7, H = f >> 12;
        int n = l & 15, g = l >> 4, C = 4 * s + g;
        float v = 0.f;
        if (C < 30) {
            int o = n >> 1, dx = n & 1, kx = e - dx;
            if (kx >= 0 && kx <= 4) {
                int c = C / 5, ky = C % 5, oc = 8 * H + o;
                v = rintf(w2[((oc * 6 + c) * 5 + ky) * 5 + kx] / get_scale(slots, 6));
            }
        }
        bf2[f] = (unsigned short)f2bf(v);
    } else if (idx < 65536) {             // conv3: [Nt8][S13][64][8]
        int f = idx - 12288, e = f & 7, l = (f >> 3) & 63, r = f >> 9;
        int s = r % 13, Nt = r / 13;
        int oc = Nt * 16 + (l & 15), k = 32 * s + 8 * (l >> 4) + e;
        float v = 0.f;
        if (oc < 120 && k < 400) v = rintf(w3[oc * 400 + k] / get_scale(slots, 7));
        bf3[f] = (unsigned short)f2bf(v);
    } else if (idx < 77824) {             // fc4: [Nt6][S4][64][8]
        int f = idx - 65536, e = f & 7, l = (f >> 3) & 63, r = f >> 9;
        int s = r & 3, Nt = r >> 2;
        int oc = Nt * 16 + (l & 15), k = 32 * s + 8 * (l >> 4) + e;
        float v = 0.f;
        if (oc < 84 && k < 120) v = rintf(w4[oc * 120 + k] / get_scale(slots, 8));
        bf4[f] = (unsigned short)f2bf(v);
    } else if (idx < 78664) {
        int i = idx - 77824;
        qw5[i] = rintf(w5[i] / get_scale(slots, 9));
    }
}

// ---------------- conv1 MFMA: [B,3,32,32] -> [B,6,14,14], 16 img/block ----------------
__global__ __launch_bounds__(512) void k_conv1(
    const float* __restrict__ x, const unsigned short* __restrict__ bf1,
    const unsigned* __restrict__ slots, unsigned* __restrict__ slot_out,
    float* __restrict__ h1)
{
    __shared__ unsigned short xs[16 * IMG1];
    __shared__ float red[8];
    int b0 = blockIdx.x * 16, tid = threadIdx.x;
    float sx = get_scale(slots, 0);
    for (int i = tid; i < 24576; i += 512) {           // pair-index staging
        int img = i / 1536, r = i % 1536;
        int c = r >> 9, rem = r & 511, yy = rem >> 4, c2 = (rem & 15) << 1;
        float2 v = *(const float2*)(x + (long)(b0 + img) * 3072 + c * 1024 + yy * 32 + c2);
        unsigned pk = f2bf(rintf(v.x / sx)) | (f2bf(rintf(v.y / sx)) << 16);
        *(unsigned*)&xs[img * IMG1 + c * 1024 + yy * 32 + c2] = pk;
    }
    __syncthreads();
    float mscale = sx * get_scale(slots, 5);
    int lane = tid & 63, wid = tid >> 6;
    int il = lane & 15, g = lane >> 4;
    short8 Bf[2][4];
    #pragma unroll
    for (int H = 0; H < 2; H++)
        #pragma unroll
        for (int s = 0; s < 4; s++)
            Bf[H][s] = *(const short8*)(bf1 + ((H * 4 + s) * 64 + lane) * 8);
    int abase[4];
    #pragma unroll
    for (int s = 0; s < 4; s++) {
        int C = 4 * s + g; if (C > 14) C = 14;
        abase[s] = il * IMG1 + (C / 5) * 1024 + (C % 5) * 32;
    }
    int n = il, o = n >> 2, dx = n & 3;
    bool doSt = ((n & 1) == 0) && (n < 12);
    float vmax = 0.f;
    for (int u = wid; u < 98; u += 8) {
        int pb = u / 14, py = u % 14;
        f32x4 acc[2][2];
        #pragma unroll
        for (int H = 0; H < 2; H++)
            #pragma unroll
            for (int yo = 0; yo < 2; yo++) acc[H][yo] = (f32x4){0.f, 0.f, 0.f, 0.f};
        #pragma unroll
        for (int yo = 0; yo < 2; yo++) {
            int y = 2 * py + yo;
            #pragma unroll
            for (int s = 0; s < 4; s++) {
                int addr = abase[s] + y * 32 + 4 * pb;
                union { unsigned long long q[2]; short8 v; } tA;
                tA.q[0] = *(const unsigned long long*)(xs + addr);
                tA.q[1] = *(const unsigned long long*)(xs + addr + 4);
                acc[0][yo] = __builtin_amdgcn_mfma_f32_16x16x32_bf16(tA.v, Bf[0][s], acc[0][yo], 0, 0, 0);
                acc[1][yo] = __builtin_amdgcn_mfma_f32_16x16x32_bf16(tA.v, Bf[1][s], acc[1][yo], 0, 0, 0);
            }
        }
        #pragma unroll
        for (int H = 0; H < 2; H++)
            #pragma unroll
            for (int r = 0; r < 4; r++) {
                float m = fmaxf(acc[H][0][r], acc[H][1][r]);   // pool over y-pair
                float pooled = fmaxf(m, __shfl_xor(m, 1));     // pool over dx-pair
                if (doSt) {
                    float v = fmaxf(pooled * mscale, 0.f);
                    int img = 4 * g + r, oc = 3 * H + o, px = 2 * pb + (dx >> 1);
                    h1[((long)(b0 + img) * 6 + oc) * 196 + py * 14 + px] = v;
                    vmax = fmaxf(vmax, v);
                }
            }
    }
    vmax = block_maxN(vmax, red, 8);
    if (tid == 0) atomicMax(slot_out, __float_as_uint(vmax));
}

// ---------------- conv2 MFMA: [B,6,14,14] -> [B,16,5,5], 16 img/block ----------------
__global__ __launch_bounds__(256) void k_conv2(
    const float* __restrict__ h1, const unsigned short* __restrict__ bf2,
    const unsigned* __restrict__ slots, unsigned* __restrict__ slot_out,
    float* __restrict__ h2)
{
    __shared__ unsigned short xs[16 * IMG2];
    __shared__ float red[4];
    int b0 = blockIdx.x * 16, tid = threadIdx.x;
    float s1 = get_scale(slots, 1);
    for (int i = tid; i < 21504; i += 256) {
        int img = i / 1344, r = i % 1344;
        int c = r / 224, rr = r % 224, yy = rr >> 4, col = rr & 15;
        float v = 0.f;
        if (col < 14) v = rintf(h1[(long)(b0 + img) * 1176 + c * 196 + yy * 14 + col] / s1);
        xs[img * IMG2 + c * 224 + yy * 16 + col] = (unsigned short)f2bf(v);
    }
    __syncthreads();
    float mscale = s1 * get_scale(slots, 6);
    int lane = tid & 63, wid = tid >> 6;
    int il = lane & 15, g = lane >> 4;
    short8 Bf[2][8];
    #pragma unroll
    for (int H = 0; H < 2; H++)
        #pragma unroll
        for (int s = 0; s < 8; s++)
            Bf[H][s] = *(const short8*)(bf2 + ((H * 8 + s) * 64 + lane) * 8);
    int abase[8];
    #pragma unroll
    for (int s = 0; s < 8; s++) {
        int C = 4 * s + g; if (C > 29) C = 29;
        abase[s] = il * IMG2 + (C / 5) * 224 + (C % 5) * 16;
    }
    int n = il, o = n >> 1;
    bool doSt = ((n & 1) == 0);
    float vmax = 0.f;
    for (int u = wid; u < 25; u += 4) {
        int pb = u / 5, py = u % 5;
        f32x4 acc[2][2];
        #pragma unroll
        for (int H = 0; H < 2; H++)
            #pragma unroll
            for (int yo = 0; yo < 2; yo++) acc[H][yo] = (f32x4){0.f, 0.f, 0.f, 0.f};
        #pragma unroll
        for (int yo = 0; yo < 2; yo++) {
            int y = 2 * py + yo;
            #pragma unroll
            for (int s = 0; s < 8; s++) {
                int addr = abase[s] + y * 16 + 2 * pb;
                union { unsigned u[4]; short8 v; } tA;
                tA.u[0] = *(const unsigned*)(xs + addr);
                tA.u[1] = *(const unsigned*)(xs + addr + 2);
                tA.u[2] = *(const unsigned*)(xs + addr + 4);
                tA.u[3] = *(const unsigned*)(xs + addr + 6);
                acc[0][yo] = __builtin_amdgcn_mfma_f32_16x16x32_bf16(tA.v, Bf[0][s], acc[0][yo], 0, 0, 0);
                acc[1][yo] = __builtin_amdgcn_mfma_f32_16x16x32_bf16(tA.v, Bf[1][s], acc[1][yo], 0, 0, 0);
            }
        }
        #pragma unroll
        for (int H = 0; H < 2; H++)
            #pragma unroll
            for (int r = 0; r < 4; r++) {
                float m = fmaxf(acc[H][0][r], acc[H][1][r]);
                float pooled = fmaxf(m, __shfl_xor(m, 1));
                if (doSt) {
                    float v = fmaxf(pooled * mscale, 0.f);
                    int img = 4 * g + r, oc = 8 * H + o;
                    h2[((long)(b0 + img) * 16 + oc) * 25 + py * 5 + pb] = v;
                    vmax = fmaxf(vmax, v);
                }
            }
    }
    vmax = block_maxN(vmax, red, 4);
    if (tid == 0) atomicMax(slot_out, __float_as_uint(vmax));
}

// ---------------- conv3 MFMA GEMM: [B,400] x [120,400] -> [B,120], 16 img/block ----------------
__global__ __launch_bounds__(256) void k_conv3(
    const float* __restrict__ h2, const unsigned short* __restrict__ bf3,
    const unsigned* __restrict__ slots, unsigned* __restrict__ slot_out,
    float* __restrict__ h3)
{
    __shared__ unsigned short xs[16 * 408];
    __shared__ float red[4];
    int b0 = blockIdx.x * 16, tid = threadIdx.x;
    float s2 = get_scale(slots, 2);
    for (int i = tid; i < 3200; i += 256) {
        int img = i / 200, p = i % 200;
        float2 v = *(const float2*)(h2 + (long)(b0 + img) * 400 + 2 * p);
        unsigned pk = f2bf(rintf(v.x / s2)) | (f2bf(rintf(v.y / s2)) << 16);
        *(unsigned*)&xs[img * 408 + 2 * p] = pk;
    }
    __syncthreads();
    float mscale = s2 * get_scale(slots, 7);
    int lane = tid & 63, wid = tid >> 6;
    int il = lane & 15, g = lane >> 4;
    f32x4 acc[2];
    acc[0] = (f32x4){0.f, 0.f, 0.f, 0.f};
    acc[1] = (f32x4){0.f, 0.f, 0.f, 0.f};
    #pragma unroll
    for (int s = 0; s < 13; s++) {
        int C = 4 * s + g; if (C > 49) C = 49;
        int addr = il * 408 + 8 * C;
        union { unsigned long long q[2]; short8 v; } tA;
        tA.q[0] = *(const unsigned long long*)(xs + addr);
        tA.q[1] = *(const unsigned long long*)(xs + addr + 4);
        #pragma unroll
        for (int t = 0; t < 2; t++) {
            int Nt = wid + 4 * t;
            short8 b = *(const short8*)(bf3 + ((Nt * 13 + s) * 64 + lane) * 8);
            acc[t] = __builtin_amdgcn_mfma_f32_16x16x32_bf16(tA.v, b, acc[t], 0, 0, 0);
        }
    }
    float vmax = 0.f;
    #pragma unroll
    for (int t = 0; t < 2; t++) {
        int oc = (wid + 4 * t) * 16 + il;
        if (oc < 120) {
            #pragma unroll
            for (int r = 0; r < 4; r++) {
                float v = fmaxf(acc[t][r] * mscale, 0.f);
                h3[(long)(b0 + 4 * g + r) * 120 + oc] = v;
                vmax = fmaxf(vmax, v);
            }
        }
    }
    vmax = block_maxN(vmax, red, 4);
    if (tid == 0) atomicMax(slot_out, __float_as_uint(vmax));
}

// ---------------- fc4 MFMA GEMM: [B,120] x [84,120] -> [B,84], 16 img/block ----------------
__global__ __launch_bounds__(256) void k_fc4(
    const float* __restrict__ h3, const unsigned short* __restrict__ bf4,
    const unsigned* __restrict__ slots, unsigned* __restrict__ slot_out,
    float* __restrict__ h4)
{
    __shared__ unsigned short xs[16 * 136];
    __shared__ float red[4];
    int b0 = blockIdx.x * 16, tid = threadIdx.x;
    float s3 = get_scale(slots, 3);
    for (int i = tid; i < 960; i += 256) {
        int img = i / 60, p = i % 60;
        float2 v = *(const float2*)(h3 + (long)(b0 + img) * 120 + 2 * p);
        unsigned pk = f2bf(rintf(v.x / s3)) | (f2bf(rintf(v.y / s3)) << 16);
        *(unsigned*)&xs[img * 136 + 2 * p] = pk;
    }
    __syncthreads();
    float mscale = s3 * get_scale(slots, 8);
    int lane = tid & 63, wid = tid >> 6;
    int il = lane & 15, g = lane >> 4;
    f32x4 acc[2];
    acc[0] = (f32x4){0.f, 0.f, 0.f, 0.f};
    acc[1] = (f32x4){0.f, 0.f, 0.f, 0.f};
    #pragma unroll
    for (int s = 0; s < 4; s++) {
        int C = 4 * s + g; if (C > 14) C = 14;
        int addr = il * 136 + 8 * C;
        union { unsigned long long q[2]; short8 v; } tA;
        tA.q[0] = *(const unsigned long long*)(xs + addr);
        tA.q[1] = *(const unsigned long long*)(xs + addr + 4);
        #pragma unroll
        for (int t = 0; t < 2; t++) {
            int Nt = wid + 4 * t;
            if (Nt < 6) {
                short8 b = *(const short8*)(bf4 + ((Nt * 4 + s) * 64 + lane) * 8);
                acc[t] = __builtin_amdgcn_mfma_f32_16x16x32_bf16(tA.v, b, acc[t], 0, 0, 0);
            }
        }
    }
    float vmax = 0.f;
    #pragma unroll
    for (int t = 0; t < 2; t++) {
        int oc = (wid + 4 * t) * 16 + il;
        if (oc < 84) {
            #pragma unroll
            for (int r = 0; r < 4; r++) {
                float v = fmaxf(acc[t][r] * mscale, 0.f);
                h4[(long)(b0 + 4 * g + r) * 84 + oc] = v;
                vmax = fmaxf(vmax, v);
            }
        }
    }
    vmax = block_maxN(vmax, red, 4);
    if (tid == 0) atomicMax(slot_out, __float_as_uint(vmax));
}

// ---------------- fc5 (VALU): [B,84] x [10,84] -> out [B,10] ----------------
__global__ __launch_bounds__(256) void k_fc5(
    const float* __restrict__ h4, const float* __restrict__ qw5,
    const unsigned* __restrict__ slots, float* __restrict__ out)
{
    __shared__ float wt[840];
    int tid = threadIdx.x;
    int gid = blockIdx.x * 256 + tid;
    float s4 = get_scale(slots, 4);
    for (int i = tid; i < 840; i += 256) wt[i] = qw5[i];
    __syncthreads();
    float mscale = s4 * get_scale(slots, 9);
    int img = gid / 10, oc = gid % 10;
    if (img < 4096) {
        float acc = 0.0f;
        const float* xr = h4 + (long)img * 84;
        const float* wr = &wt[oc * 84];
        for (int k = 0; k < 84; k++) acc += rintf(xr[k] / s4) * wr[k];
        out[gid] = acc * mscale;
    }
}

extern "C" void kernel_launch(void* const* d_in, const int* in_sizes, int n_in,
                              void* d_out, int out_size, void* d_ws, size_t ws_size,
                              hipStream_t stream) {
    const float* x  = (const float*)d_in[0];
    const float* w1 = (const float*)d_in[1];
    const float* w2 = (const float*)d_in[2];
    const float* w3 = (const float*)d_in[3];
    const float* w4 = (const float*)d_in[4];
    const float* w5 = (const float*)d_in[5];
    float* out = (float*)d_out;
    float* ws = (float*)d_ws;
    unsigned* slots = (unsigned*)d_ws;
    float* qw5 = ws + OFF_QW5;
    unsigned short* bf1 = (unsigned short*)(ws + OFF_BF1);
    unsigned short* bf2 = (unsigned short*)(ws + OFF_BF2);
    unsigned short* bf3 = (unsigned short*)(ws + OFF_BF3);
    unsigned short* bf4 = (unsigned short*)(ws + OFF_BF4);
    float* h1 = ws + OFF_H1;
    float* h2 = ws + OFF_H2;
    float* h3 = ws + OFF_H3;
    float* h4 = ws + OFF_H4;

    hipMemsetAsync(d_ws, 0, 64, stream);   // zero the 16 absmax slots
    k_absmax_all<<<2112, 256, 0, stream>>>((const float4*)x, w1, w2, w3, w4, w5, slots);
    k_bfrag<<<308, 256, 0, stream>>>(w1, w2, w3, w4, w5, slots, bf1, bf2, bf3, bf4, qw5);
    k_conv1<<<256, 512, 0, stream>>>(x, bf1, slots, slots + 1, h1);
    k_conv2<<<256, 256, 0, stream>>>(h1, bf2, slots, slots + 2, h2);
    k_conv3<<<256, 256, 0, stream>>>(h2, bf3, slots, slots + 3, h3);
    k_fc4<<<256, 256, 0, stream>>>(h3, bf4, slots, slots + 4, h4);
    k_fc5<<<160, 256, 0, stream>>>(h4, qw5, slots, out);
}

// Round 5
// 119.641 us; speedup vs baseline: 2.5533x; 1.2720x over previous
//
#include <hip/hip_runtime.h>
#include <hip/hip_bf16.h>

#define QMAX 255.0f

typedef __attribute__((ext_vector_type(8))) short short8;
typedef __attribute__((ext_vector_type(4))) float f32x4;

// ws float offsets
#define OFF_BF1   16       // ushort[4096]  -> 2048 floats
#define OFF_BF2   2064     // ushort[8192]  -> 4096 floats
#define OFF_BF3   6160     // ushort[53248] -> 26624 floats
#define OFF_BF4   32784    // ushort[12288] -> 6144 floats
#define OFF_BF5   38928    // ushort[1536]  -> 768 floats
#define OFF_H1    40960    // padded f32 [4096][6][14][16] = 5505024 -> ends 5545984
#define OFF_H2    5545984  // f32 [4096][400] = 1638400 -> ends 7184384 (28.7 MB high water)
#define OFF_H3    40960    // reuses dead h1 region: f32 [4096][120] = 491520
#define OFF_H4    532480   // f32 [4096][84] = 344064 (still inside old h1 region)

#define IMG1 3076   // shorts per image, conv1 LDS
#define IMG2 1348   // shorts per image, conv2 LDS

__device__ __forceinline__ float get_scale(const unsigned* slots, int i) {
    float amax = __uint_as_float(slots[i]);
    float s = amax / QMAX;
    if (!(s > 0.0f)) s = 1.0f;
    return s;
}
__device__ __forceinline__ unsigned f2bf(float f) { return __float_as_uint(f) >> 16; } // exact for our ints

__device__ __forceinline__ float block_maxN(float v, float* red, int nw) {
    #pragma unroll
    for (int off = 32; off > 0; off >>= 1) v = fmaxf(v, __shfl_xor(v, off));
    if ((threadIdx.x & 63) == 0) red[threadIdx.x >> 6] = v;
    __syncthreads();
    float m = red[0];
    for (int i = 1; i < nw; i++) m = fmaxf(m, red[i]);
    return m;
}

// ---------------- absmax: x (blocks 0..2047) + all 5 weights ----------------
__global__ __launch_bounds__(256) void k_absmax_all(
    const float4* __restrict__ x4,
    const float* __restrict__ w1, const float* __restrict__ w2,
    const float* __restrict__ w3, const float* __restrict__ w4,
    const float* __restrict__ w5, unsigned* __restrict__ slots)
{
    __shared__ float red[4];
    int b = blockIdx.x, tid = threadIdx.x;
    float m = 0.0f;
    int slot = -1;
    if (b < 2048) {
        slot = 0;
        for (int i = b * 256 + tid; i < 3145728; i += 2048 * 256) {
            float4 v = x4[i];
            m = fmaxf(m, fmaxf(fmaxf(fabsf(v.x), fabsf(v.y)), fmaxf(fabsf(v.z), fabsf(v.w))));
        }
    } else {
        int b2 = b - 2048;
        const float* w = nullptr; int n = 0, start = 0, stride = 256;
        if (b2 < 48)      { w = w3; n = 48000; start = b2 * 256;        stride = 48 * 256; slot = 7; }
        else if (b2 < 58) { w = w4; n = 10080; start = (b2 - 48) * 256; stride = 10 * 256; slot = 8; }
        else if (b2 == 58){ w = w2; n = 2400;  slot = 6; }
        else if (b2 == 59){ w = w1; n = 450;   slot = 5; }
        else if (b2 == 60){ w = w5; n = 840;   slot = 9; }
        if (slot >= 0)
            for (int i = start + tid; i < n; i += stride) m = fmaxf(m, fabsf(w[i]));
    }
    m = block_maxN(m, red, 4);
    if (tid == 0 && slot >= 0) atomicMax(&slots[slot], __float_as_uint(m));
}

// ---------------- build MFMA B-fragments ----------------
__global__ __launch_bounds__(256) void k_bfrag(
    const float* __restrict__ w1, const float* __restrict__ w2,
    const float* __restrict__ w3, const float* __restrict__ w4,
    const float* __restrict__ w5, const unsigned* __restrict__ slots,
    unsigned short* __restrict__ bf1, unsigned short* __restrict__ bf2,
    unsigned short* __restrict__ bf3, unsigned short* __restrict__ bf4,
    unsigned short* __restrict__ bf5)
{
    int idx = blockIdx.x * 256 + threadIdx.x;
    if (idx < 4096) {                     // conv1: [H2][S4][64][8], n=o*4+dx (o<3,dx<4)
        int f = idx, e = f & 7, l = (f >> 3) & 63, s = (f >> 9) & 3, H = f >> 11;
        int n = l & 15, g = l >> 4, C = 4 * s + g;
        float v = 0.f;
        if (n < 12 && C < 15) {
            int o = n >> 2, dx = n & 3, kx = e - dx;
            if (kx >= 0 && kx <= 4) {
                int c = C / 5, ky = C % 5, oc = 3 * H + o;
                v = rintf(w1[((oc * 3 + c) * 5 + ky) * 5 + kx] / get_scale(slots, 5));
            }
        }
        bf1[f] = (unsigned short)f2bf(v);
    } else if (idx < 12288) {             // conv2: [H2][S8][64][8], n=o*2+dx (o<8,dx<2)
        int f = idx - 4096, e = f & 7, l = (f >> 3) & 63, s = (f >> 9) & 7, H = f >> 12;
        int n = l & 15, g = l >> 4, C = 4 * s + g;
        float v = 0.f;
        if (C < 30) {
            int o = n >> 1, dx = n & 1, kx = e - dx;
            if (kx >= 0 && kx <= 4) {
                int c = C / 5, ky = C % 5, oc = 8 * H + o;
                v = rintf(w2[((oc * 6 + c) * 5 + ky) * 5 + kx] / get_scale(slots, 6));
            }
        }
        bf2[f] = (unsigned short)f2bf(v);
    } else if (idx < 65536) {             // conv3: [Nt8][S13][64][8]
        int f = idx - 12288, e = f & 7, l = (f >> 3) & 63, r = f >> 9;
        int s = r % 13, Nt = r / 13;
        int oc = Nt * 16 + (l & 15), k = 32 * s + 8 * (l >> 4) + e;
        float v = 0.f;
        if (oc < 120 && k < 400) v = rintf(w3[oc * 400 + k] / get_scale(slots, 7));
        bf3[f] = (unsigned short)f2bf(v);
    } else if (idx < 77824) {             // fc4: [Nt6][S4][64][8]
        int f = idx - 65536, e = f & 7, l = (f >> 3) & 63, r = f >> 9;
        int s = r & 3, Nt = r >> 2;
        int oc = Nt * 16 + (l & 15), k = 32 * s + 8 * (l >> 4) + e;
        float v = 0.f;
        if (oc < 84 && k < 120) v = rintf(w4[oc * 120 + k] / get_scale(slots, 8));
        bf4[f] = (unsigned short)f2bf(v);
    } else if (idx < 79360) {             // fc5: [S3][64][8]
        int f = idx - 77824, e = f & 7, l = (f >> 3) & 63, s = f >> 9;
        int oc = l & 15, k = 32 * s + 8 * (l >> 4) + e;
        float v = 0.f;
        if (oc < 10 && k < 84) v = rintf(w5[oc * 84 + k] / get_scale(slots, 9));
        bf5[f] = (unsigned short)f2bf(v);
    }
}

// ---------------- conv1 MFMA: [B,3,32,32] -> padded h1 [B,6,14,16], 4 img/block ----------------
// M-row il = 4*img + q (q = position quarter of the 98 pool blocks); waves split uu.
__global__ __launch_bounds__(256) void k_conv1(
    const float* __restrict__ x, const unsigned short* __restrict__ bf1,
    const unsigned* __restrict__ slots, unsigned* __restrict__ slot_out,
    float* __restrict__ h1)
{
    __shared__ unsigned short xs[4 * IMG1];
    __shared__ float red[4];
    int b0 = blockIdx.x * 4, tid = threadIdx.x;
    int lane = tid & 63, wid = tid >> 6;
    int il = lane & 15, g = lane >> 4;
    // B fragments (global, independent of staging)
    short8 Bf[2][4];
    #pragma unroll
    for (int H = 0; H < 2; H++)
        #pragma unroll
        for (int s = 0; s < 4; s++)
            Bf[H][s] = *(const short8*)(bf1 + ((H * 4 + s) * 64 + lane) * 8);
    float sx = get_scale(slots, 0);
    #pragma unroll
    for (int img = 0; img < 4; img++) {
        const float* xb = x + (long)(b0 + img) * 3072;
        for (int i = tid; i < 1536; i += 256) {
            int c = i >> 9, rem = i & 511, yy = rem >> 4, c2 = (rem & 15) << 1;
            float2 v = *(const float2*)(xb + c * 1024 + yy * 32 + c2);
            unsigned pk = f2bf(rintf(v.x / sx)) | (f2bf(rintf(v.y / sx)) << 16);
            *(unsigned*)&xs[img * IMG1 + c * 1024 + yy * 32 + c2] = pk;
        }
    }
    // zero-fill padded cols 14,15 of h1 for this block's images
    for (int i = tid; i < 336; i += 256) {
        int img = i / 84, rem = i % 84, c = rem / 14, py = rem % 14;
        *(float2*)(h1 + ((long)(b0 + img) * 6 + c) * 224 + py * 16 + 14) = make_float2(0.f, 0.f);
    }
    __syncthreads();
    float mscale = sx * get_scale(slots, 5);

    int abase[4];
    #pragma unroll
    for (int s = 0; s < 4; s++) {
        int C = 4 * s + g; if (C > 14) C = 14;
        abase[s] = (il >> 2) * IMG1 + (C / 5) * 1024 + (C % 5) * 32;
    }
    int q = il & 3;
    int offq = (q < 2) ? 25 * q : (q == 2 ? 50 : 74);
    int n = il, o = n >> 2, dx = n & 3;
    bool doStCol = ((n & 1) == 0) && (n < 12);
    float vmax = 0.f;
    for (int uu = wid; uu < 25; uu += 4) {
        int p = offq + uu; if (p > 97) p = 97;
        int pb = p / 14, py = p % 14;            // read-side (per-lane)
        f32x4 acc[2][2];
        #pragma unroll
        for (int H = 0; H < 2; H++)
            #pragma unroll
            for (int yo = 0; yo < 2; yo++) acc[H][yo] = (f32x4){0.f, 0.f, 0.f, 0.f};
        #pragma unroll
        for (int yo = 0; yo < 2; yo++) {
            int y = 2 * py + yo;
            #pragma unroll
            for (int s = 0; s < 4; s++) {
                int addr = abase[s] + y * 32 + 4 * pb;
                union { unsigned long long u[2]; short8 v; } tA;
                tA.u[0] = *(const unsigned long long*)(xs + addr);
                tA.u[1] = *(const unsigned long long*)(xs + addr + 4);
                acc[0][yo] = __builtin_amdgcn_mfma_f32_16x16x32_bf16(tA.v, Bf[0][s], acc[0][yo], 0, 0, 0);
                acc[1][yo] = __builtin_amdgcn_mfma_f32_16x16x32_bf16(tA.v, Bf[1][s], acc[1][yo], 0, 0, 0);
            }
        }
        #pragma unroll
        for (int H = 0; H < 2; H++)
            #pragma unroll
            for (int r = 0; r < 4; r++) {
                float m = fmaxf(acc[H][0][r], acc[H][1][r]);      // pool over y-pair
                float pooled = fmaxf(m, __shfl_xor(m, 1));        // pool over dx-pair
                int cntr = (r < 2) ? 25 : 24;
                if (doStCol && uu < cntr) {
                    int offr = (r < 2) ? 25 * r : (r == 2 ? 50 : 74);
                    int pr = offr + uu, pbr = pr / 14, pyr = pr % 14;
                    float v = fmaxf(pooled * mscale, 0.f);
                    int oc = 3 * H + o, px = 2 * pbr + (dx >> 1);
                    h1[((long)(b0 + g) * 6 + oc) * 224 + pyr * 16 + px] = v;
                    vmax = fmaxf(vmax, v);
                }
            }
    }
    vmax = block_maxN(vmax, red, 4);
    if (tid == 0) atomicMax(slot_out, __float_as_uint(vmax));
}

// ---------------- conv2 MFMA: padded h1 -> [B,16,25], 4 img/block ----------------
// M-row il = 4*img + q (q = quarter of 25 pool positions); waves split uu (0..6).
__global__ __launch_bounds__(256) void k_conv2(
    const float* __restrict__ h1, const unsigned short* __restrict__ bf2,
    const unsigned* __restrict__ slots, unsigned* __restrict__ slot_out,
    float* __restrict__ h2)
{
    __shared__ unsigned short xs[4 * IMG2];
    __shared__ float red[4];
    int b0 = blockIdx.x * 4, tid = threadIdx.x;
    int lane = tid & 63, wid = tid >> 6;
    int il = lane & 15, g = lane >> 4;
    short8 Bf[2][8];
    #pragma unroll
    for (int H = 0; H < 2; H++)
        #pragma unroll
        for (int s = 0; s < 8; s++)
            Bf[H][s] = *(const short8*)(bf2 + ((H * 8 + s) * 64 + lane) * 8);
    float s1 = get_scale(slots, 1);
    #pragma unroll
    for (int img = 0; img < 4; img++) {
        const float4* src = (const float4*)(h1 + (long)(b0 + img) * 1344);
        for (int i = tid; i < 336; i += 256) {
            float4 v = src[i];
            unsigned pk0 = f2bf(rintf(v.x / s1)) | (f2bf(rintf(v.y / s1)) << 16);
            unsigned pk1 = f2bf(rintf(v.z / s1)) | (f2bf(rintf(v.w / s1)) << 16);
            *(uint2*)&xs[img * IMG2 + 4 * i] = make_uint2(pk0, pk1);
        }
    }
    __syncthreads();
    float mscale = s1 * get_scale(slots, 6);

    int abase[8];
    #pragma unroll
    for (int s = 0; s < 8; s++) {
        int C = 4 * s + g; if (C > 29) C = 29;
        abase[s] = (il >> 2) * IMG2 + (C / 5) * 224 + (C % 5) * 16;
    }
    int q = il & 3;
    int offq = (q == 0) ? 0 : (6 * q + 1);   // {0,7,13,19}
    int n = il, o = n >> 1;
    bool doStCol = ((n & 1) == 0);
    float vmax = 0.f;
    for (int uu = wid; uu < 7; uu += 4) {
        int p = offq + uu; if (p > 24) p = 24;
        int pb = p / 5, py = p % 5;
        f32x4 acc[2][2];
        #pragma unroll
        for (int H = 0; H < 2; H++)
            #pragma unroll
            for (int yo = 0; yo < 2; yo++) acc[H][yo] = (f32x4){0.f, 0.f, 0.f, 0.f};
        #pragma unroll
        for (int yo = 0; yo < 2; yo++) {
            int y = 2 * py + yo;
            #pragma unroll
            for (int s = 0; s < 8; s++) {
                int addr = abase[s] + y * 16 + 2 * pb;
                union { unsigned u[4]; short8 v; } tA;
                tA.u[0] = *(const unsigned*)(xs + addr);
                tA.u[1] = *(const unsigned*)(xs + addr + 2);
                tA.u[2] = *(const unsigned*)(xs + addr + 4);
                tA.u[3] = *(const unsigned*)(xs + addr + 6);
                acc[0][yo] = __builtin_amdgcn_mfma_f32_16x16x32_bf16(tA.v, Bf[0][s], acc[0][yo], 0, 0, 0);
                acc[1][yo] = __builtin_amdgcn_mfma_f32_16x16x32_bf16(tA.v, Bf[1][s], acc[1][yo], 0, 0, 0);
            }
        }
        #pragma unroll
        for (int H = 0; H < 2; H++)
            #pragma unroll
            for (int r = 0; r < 4; r++) {
                float m = fmaxf(acc[H][0][r], acc[H][1][r]);
                float pooled = fmaxf(m, __shfl_xor(m, 1));
                int cntr = (r == 0) ? 7 : 6;
                if (doStCol && uu < cntr) {
                    int offr = (r == 0) ? 0 : (6 * r + 1);
                    int pr = offr + uu, pbr = pr / 5, pyr = pr % 5;
                    float v = fmaxf(pooled * mscale, 0.f);
                    int oc = 8 * H + o;
                    h2[((long)(b0 + g) * 16 + oc) * 25 + pyr * 5 + pbr] = v;
                    vmax = fmaxf(vmax, v);
                }
            }
    }
    vmax = block_maxN(vmax, red, 4);
    if (tid == 0) atomicMax(slot_out, __float_as_uint(vmax));
}

// ---------------- conv3 MFMA GEMM: [B,400]x[120,400] -> [B,120], 16 img/block, 8 waves ----------------
__global__ __launch_bounds__(512) void k_conv3(
    const float* __restrict__ h2, const unsigned short* __restrict__ bf3,
    const unsigned* __restrict__ slots, unsigned* __restrict__ slot_out,
    float* __restrict__ h3)
{
    __shared__ unsigned short xs[16 * 408];
    __shared__ float red[8];
    int b0 = blockIdx.x * 16, tid = threadIdx.x;
    int lane = tid & 63, wid = tid >> 6;
    int il = lane & 15, g = lane >> 4;
    short8 Bf[13];
    #pragma unroll
    for (int s = 0; s < 13; s++)
        Bf[s] = *(const short8*)(bf3 + ((wid * 13 + s) * 64 + lane) * 8);
    float s2 = get_scale(slots, 2);
    for (int i = tid; i < 3200; i += 512) {
        int img = i / 200, p = i % 200;
        float2 v = *(const float2*)(h2 + (long)(b0 + img) * 400 + 2 * p);
        unsigned pk = f2bf(rintf(v.x / s2)) | (f2bf(rintf(v.y / s2)) << 16);
        *(unsigned*)&xs[img * 408 + 2 * p] = pk;
    }
    __syncthreads();
    float mscale = s2 * get_scale(slots, 7);
    f32x4 acc = (f32x4){0.f, 0.f, 0.f, 0.f};
    #pragma unroll
    for (int s = 0; s < 13; s++) {
        int C = 4 * s + g; if (C > 49) C = 49;
        int addr = il * 408 + 8 * C;
        union { unsigned long long u[2]; short8 v; } tA;
        tA.u[0] = *(const unsigned long long*)(xs + addr);
        tA.u[1] = *(const unsigned long long*)(xs + addr + 4);
        acc = __builtin_amdgcn_mfma_f32_16x16x32_bf16(tA.v, Bf[s], acc, 0, 0, 0);
    }
    float vmax = 0.f;
    int oc = wid * 16 + il;
    if (oc < 120) {
        #pragma unroll
        for (int r = 0; r < 4; r++) {
            float v = fmaxf(acc[r] * mscale, 0.f);
            h3[(long)(b0 + 4 * g + r) * 120 + oc] = v;
            vmax = fmaxf(vmax, v);
        }
    }
    vmax = block_maxN(vmax, red, 8);
    if (tid == 0) atomicMax(slot_out, __float_as_uint(vmax));
}

// ---------------- fc4 MFMA GEMM: [B,120]x[84,120] -> [B,84], 16 img/block, 8 waves ----------------
__global__ __launch_bounds__(512) void k_fc4(
    const float* __restrict__ h3, const unsigned short* __restrict__ bf4,
    const unsigned* __restrict__ slots, unsigned* __restrict__ slot_out,
    float* __restrict__ h4)
{
    __shared__ unsigned short xs[16 * 136];
    __shared__ float red[8];
    int b0 = blockIdx.x * 16, tid = threadIdx.x;
    int lane = tid & 63, wid = tid >> 6;
    int il = lane & 15, g = lane >> 4;
    short8 Bf[4];
    if (wid < 6) {
        #pragma unroll
        for (int s = 0; s < 4; s++)
            Bf[s] = *(const short8*)(bf4 + ((wid * 4 + s) * 64 + lane) * 8);
    }
    float s3 = get_scale(slots, 3);
    for (int i = tid; i < 960; i += 512) {
        int img = i / 60, p = i % 60;
        float2 v = *(const float2*)(h3 + (long)(b0 + img) * 120 + 2 * p);
        unsigned pk = f2bf(rintf(v.x / s3)) | (f2bf(rintf(v.y / s3)) << 16);
        *(unsigned*)&xs[img * 136 + 2 * p] = pk;
    }
    __syncthreads();
    float mscale = s3 * get_scale(slots, 8);
    float vmax = 0.f;
    if (wid < 6) {
        f32x4 acc = (f32x4){0.f, 0.f, 0.f, 0.f};
        #pragma unroll
        for (int s = 0; s < 4; s++) {
            int C = 4 * s + g; if (C > 14) C = 14;
            int addr = il * 136 + 8 * C;
            union { unsigned long long u[2]; short8 v; } tA;
            tA.u[0] = *(const unsigned long long*)(xs + addr);
            tA.u[1] = *(const unsigned long long*)(xs + addr + 4);
            acc = __builtin_amdgcn_mfma_f32_16x16x32_bf16(tA.v, Bf[s], acc, 0, 0, 0);
        }
        int oc = wid * 16 + il;
        if (oc < 84) {
            #pragma unroll
            for (int r = 0; r < 4; r++) {
                float v = fmaxf(acc[r] * mscale, 0.f);
                h4[(long)(b0 + 4 * g + r) * 84 + oc] = v;
                vmax = fmaxf(vmax, v);
            }
        }
    }
    vmax = block_maxN(vmax, red, 8);
    if (tid == 0) atomicMax(slot_out, __float_as_uint(vmax));
}

// ---------------- fc5 MFMA: [B,84]x[10,84] -> out [B,10]; 4 indep waves x 16 img ----------------
__global__ __launch_bounds__(256) void k_fc5(
    const float* __restrict__ h4, const unsigned short* __restrict__ bf5,
    const unsigned* __restrict__ slots, float* __restrict__ out)
{
    __shared__ unsigned short xs[4 * 16 * 104];
    int tid = threadIdx.x;
    int lane = tid & 63, w = tid >> 6;
    int il = lane & 15, g = lane >> 4;
    int b0w = blockIdx.x * 64 + w * 16;
    short8 Bf[3];
    #pragma unroll
    for (int s = 0; s < 3; s++)
        Bf[s] = *(const short8*)(bf5 + ((s * 64) + lane) * 8);
    float s4 = get_scale(slots, 4);
    for (int i = lane; i < 672; i += 64) {
        int img = i / 42, j = i % 42;
        float2 v = *(const float2*)(h4 + (long)(b0w + img) * 84 + 2 * j);
        unsigned pk = f2bf(rintf(v.x / s4)) | (f2bf(rintf(v.y / s4)) << 16);
        *(unsigned*)&xs[w * 1664 + img * 104 + 2 * j] = pk;
    }
    for (int i = lane; i < 96; i += 64) {   // zero pad k=84..95
        int img = i / 6, j = i % 6;
        *(unsigned*)&xs[w * 1664 + img * 104 + 84 + 2 * j] = 0u;
    }
    __syncthreads();
    float mscale = s4 * get_scale(slots, 9);
    f32x4 acc = (f32x4){0.f, 0.f, 0.f, 0.f};
    #pragma unroll
    for (int s = 0; s < 3; s++) {
        int addr = w * 1664 + il * 104 + 32 * s + 8 * g;
        union { unsigned long long u[2]; short8 v; } tA;
        tA.u[0] = *(const unsigned long long*)(xs + addr);
        tA.u[1] = *(const unsigned long long*)(xs + addr + 4);
        acc = __builtin_amdgcn_mfma_f32_16x16x32_bf16(tA.v, Bf[s], acc, 0, 0, 0);
    }
    if (il < 10) {
        #pragma unroll
        for (int r = 0; r < 4; r++)
            out[(long)(b0w + 4 * g + r) * 10 + il] = acc[r] * mscale;
    }
}

extern "C" void kernel_launch(void* const* d_in, const int* in_sizes, int n_in,
                              void* d_out, int out_size, void* d_ws, size_t ws_size,
                              hipStream_t stream) {
    const float* x  = (const float*)d_in[0];
    const float* w1 = (const float*)d_in[1];
    const float* w2 = (const float*)d_in[2];
    const float* w3 = (const float*)d_in[3];
    const float* w4 = (const float*)d_in[4];
    const float* w5 = (const float*)d_in[5];
    float* out = (float*)d_out;
    float* ws = (float*)d_ws;
    unsigned* slots = (unsigned*)d_ws;
    unsigned short* bf1 = (unsigned short*)(ws + OFF_BF1);
    unsigned short* bf2 = (unsigned short*)(ws + OFF_BF2);
    unsigned short* bf3 = (unsigned short*)(ws + OFF_BF3);
    unsigned short* bf4 = (unsigned short*)(ws + OFF_BF4);
    unsigned short* bf5 = (unsigned short*)(ws + OFF_BF5);
    float* h1 = ws + OFF_H1;
    float* h2 = ws + OFF_H2;
    float* h3 = ws + OFF_H3;   // reuses h1's region (dead after conv2)
    float* h4 = ws + OFF_H4;

    hipMemsetAsync(d_ws, 0, 64, stream);   // zero the 16 absmax slots
    k_absmax_all<<<2112, 256, 0, stream>>>((const float4*)x, w1, w2, w3, w4, w5, slots);
    k_bfrag<<<310, 256, 0, stream>>>(w1, w2, w3, w4, w5, slots, bf1, bf2, bf3, bf4, bf5);
    k_conv1<<<1024, 256, 0, stream>>>(x, bf1, slots, slots + 1, h1);
    k_conv2<<<1024, 256, 0, stream>>>(h1, bf2, slots, slots + 2, h2);
    k_conv3<<<256, 512, 0, stream>>>(h2, bf3, slots, slots + 3, h3);
    k_fc4<<<256, 512, 0, stream>>>(h3, bf4, slots, slots + 4, h4);
    k_fc5<<<64, 256, 0, stream>>>(h4, bf5, slots, out);
}

// Round 6
// 117.161 us; speedup vs baseline: 2.6074x; 1.0212x over previous
//
#include <hip/hip_runtime.h>
#include <hip/hip_bf16.h>

#define QMAX 255.0f

typedef __attribute__((ext_vector_type(8))) short short8;
typedef __attribute__((ext_vector_type(4))) float f32x4;

// ws float offsets
#define OFF_BF1   16       // ushort[4096]  -> 2048 floats
#define OFF_BF2   2064     // ushort[8192]  -> 4096 floats
#define OFF_BF3   6160     // ushort[53248] -> 26624 floats
#define OFF_BF4   32784    // ushort[12288] -> 6144 floats
#define OFF_BF5   38928    // ushort[1536]  -> 768 floats
#define OFF_H1    40960    // padded f32 [4096][6][14][16] = 5505024 -> ends 5545984
#define OFF_H2    5545984  // f32 [4096][400] = 1638400 -> ends 7184384 (28.7 MB high water)
#define OFF_H3    40960    // reuses dead h1 region: f32 [4096][120] = 491520
#define OFF_H4    532480   // f32 [4096][84] = 344064 (still inside old h1 region)

#define IMG1 3088   // shorts/img conv1 LDS: 1544 dw = +8 banks per img (was +2)
#define IMG2 1360   // shorts/img conv2 LDS: 680 dw = +8 banks per img (was +2)

// bank-conflict swizzle: XOR row bits (6..8) into 16B-slot bits (3..5) of a
// short-index. Bijective within each 512-short span; preserves 2/4-short unit
// alignment. Applied identically on store and load -> layout-consistent.
__device__ __forceinline__ int swz(int L) { return L ^ (((L >> 6) & 7) << 3); }

__device__ __forceinline__ float get_scale(const unsigned* slots, int i) {
    float amax = __uint_as_float(slots[i]);
    float s = amax / QMAX;
    if (!(s > 0.0f)) s = 1.0f;
    return s;
}
__device__ __forceinline__ unsigned f2bf(float f) { return __float_as_uint(f) >> 16; } // exact for our ints

__device__ __forceinline__ float block_maxN(float v, float* red, int nw) {
    #pragma unroll
    for (int off = 32; off > 0; off >>= 1) v = fmaxf(v, __shfl_xor(v, off));
    if ((threadIdx.x & 63) == 0) red[threadIdx.x >> 6] = v;
    __syncthreads();
    float m = red[0];
    for (int i = 1; i < nw; i++) m = fmaxf(m, red[i]);
    return m;
}

// ---------------- absmax: x (blocks 0..2047) + all 5 weights ----------------
__global__ __launch_bounds__(256) void k_absmax_all(
    const float4* __restrict__ x4,
    const float* __restrict__ w1, const float* __restrict__ w2,
    const float* __restrict__ w3, const float* __restrict__ w4,
    const float* __restrict__ w5, unsigned* __restrict__ slots)
{
    __shared__ float red[4];
    int b = blockIdx.x, tid = threadIdx.x;
    float m = 0.0f;
    int slot = -1;
    if (b < 2048) {
        slot = 0;
        for (int i = b * 256 + tid; i < 3145728; i += 2048 * 256) {
            float4 v = x4[i];
            m = fmaxf(m, fmaxf(fmaxf(fabsf(v.x), fabsf(v.y)), fmaxf(fabsf(v.z), fabsf(v.w))));
        }
    } else {
        int b2 = b - 2048;
        const float* w = nullptr; int n = 0, start = 0, stride = 256;
        if (b2 < 48)      { w = w3; n = 48000; start = b2 * 256;        stride = 48 * 256; slot = 7; }
        else if (b2 < 58) { w = w4; n = 10080; start = (b2 - 48) * 256; stride = 10 * 256; slot = 8; }
        else if (b2 == 58){ w = w2; n = 2400;  slot = 6; }
        else if (b2 == 59){ w = w1; n = 450;   slot = 5; }
        else if (b2 == 60){ w = w5; n = 840;   slot = 9; }
        if (slot >= 0)
            for (int i = start + tid; i < n; i += stride) m = fmaxf(m, fabsf(w[i]));
    }
    m = block_maxN(m, red, 4);
    if (tid == 0 && slot >= 0) atomicMax(&slots[slot], __float_as_uint(m));
}

// ---------------- build MFMA B-fragments ----------------
__global__ __launch_bounds__(256) void k_bfrag(
    const float* __restrict__ w1, const float* __restrict__ w2,
    const float* __restrict__ w3, const float* __restrict__ w4,
    const float* __restrict__ w5, const unsigned* __restrict__ slots,
    unsigned short* __restrict__ bf1, unsigned short* __restrict__ bf2,
    unsigned short* __restrict__ bf3, unsigned short* __restrict__ bf4,
    unsigned short* __restrict__ bf5)
{
    int idx = blockIdx.x * 256 + threadIdx.x;
    if (idx < 4096) {                     // conv1: [H2][S4][64][8], n=o*4+dx (o<3,dx<4)
        int f = idx, e = f & 7, l = (f >> 3) & 63, s = (f >> 9) & 3, H = f >> 11;
        int n = l & 15, g = l >> 4, C = 4 * s + g;
        float v = 0.f;
        if (n < 12 && C < 15) {
            int o = n >> 2, dx = n & 3, kx = e - dx;
            if (kx >= 0 && kx <= 4) {
                int c = C / 5, ky = C % 5, oc = 3 * H + o;
                v = rintf(w1[((oc * 3 + c) * 5 + ky) * 5 + kx] / get_scale(slots, 5));
            }
        }
        bf1[f] = (unsigned short)f2bf(v);
    } else if (idx < 12288) {             // conv2: [H2][S8][64][8], n=o*2+dx (o<8,dx<2)
        int f = idx - 4096, e = f & 7, l = (f >> 3) & 63, s = (f >> 9) & 7, H = f >> 12;
        int n = l & 15, g = l >> 4, C = 4 * s + g;
        float v = 0.f;
        if (C < 30) {
            int o = n >> 1, dx = n & 1, kx = e - dx;
            if (kx >= 0 && kx <= 4) {
                int c = C / 5, ky = C % 5, oc = 8 * H + o;
                v = rintf(w2[((oc * 6 + c) * 5 + ky) * 5 + kx] / get_scale(slots, 6));
            }
        }
        bf2[f] = (unsigned short)f2bf(v);
    } else if (idx < 65536) {             // conv3: [Nt8][S13][64][8]
        int f = idx - 12288, e = f & 7, l = (f >> 3) & 63, r = f >> 9;
        int s = r % 13, Nt = r / 13;
        int oc = Nt * 16 + (l & 15), k = 32 * s + 8 * (l >> 4) + e;
        float v = 0.f;
        if (oc < 120 && k < 400) v = rintf(w3[oc * 400 + k] / get_scale(slots, 7));
        bf3[f] = (unsigned short)f2bf(v);
    } else if (idx < 77824) {             // fc4: [Nt6][S4][64][8]
        int f = idx - 65536, e = f & 7, l = (f >> 3) & 63, r = f >> 9;
        int s = r & 3, Nt = r >> 2;
        int oc = Nt * 16 + (l & 15), k = 32 * s + 8 * (l >> 4) + e;
        float v = 0.f;
        if (oc < 84 && k < 120) v = rintf(w4[oc * 120 + k] / get_scale(slots, 8));
        bf4[f] = (unsigned short)f2bf(v);
    } else if (idx < 79360) {             // fc5: [S3][64][8]
        int f = idx - 77824, e = f & 7, l = (f >> 3) & 63, s = f >> 9;
        int oc = l & 15, k = 32 * s + 8 * (l >> 4) + e;
        float v = 0.f;
        if (oc < 10 && k < 84) v = rintf(w5[oc * 84 + k] / get_scale(slots, 9));
        bf5[f] = (unsigned short)f2bf(v);
    }
}

// ---------------- conv1 MFMA: [B,3,32,32] -> padded h1 [B,6,14,16], 4 img/block ----------------
__global__ __launch_bounds__(256) void k_conv1(
    const float* __restrict__ x, const unsigned short* __restrict__ bf1,
    const unsigned* __restrict__ slots, unsigned* __restrict__ slot_out,
    float* __restrict__ h1)
{
    __shared__ unsigned short xs[4 * IMG1];
    __shared__ float red[4];
    int b0 = blockIdx.x * 4, tid = threadIdx.x;
    int lane = tid & 63, wid = tid >> 6;
    int il = lane & 15, g = lane >> 4;
    short8 Bf[2][4];
    #pragma unroll
    for (int H = 0; H < 2; H++)
        #pragma unroll
        for (int s = 0; s < 4; s++)
            Bf[H][s] = *(const short8*)(bf1 + ((H * 4 + s) * 64 + lane) * 8);
    float sx = get_scale(slots, 0);
    #pragma unroll
    for (int img = 0; img < 4; img++) {
        const float* xb = x + (long)(b0 + img) * 3072;
        for (int i = tid; i < 1536; i += 256) {
            int c = i >> 9, rem = i & 511, yy = rem >> 4, c2 = (rem & 15) << 1;
            float2 v = *(const float2*)(xb + c * 1024 + yy * 32 + c2);
            unsigned pk = f2bf(rintf(v.x / sx)) | (f2bf(rintf(v.y / sx)) << 16);
            *(unsigned*)&xs[swz(img * IMG1 + c * 1024 + yy * 32 + c2)] = pk;
        }
    }
    // zero-fill padded cols 14,15 of h1 for this block's images
    for (int i = tid; i < 336; i += 256) {
        int img = i / 84, rem = i % 84, c = rem / 14, py = rem % 14;
        *(float2*)(h1 + ((long)(b0 + img) * 6 + c) * 224 + py * 16 + 14) = make_float2(0.f, 0.f);
    }
    __syncthreads();
    float mscale = sx * get_scale(slots, 5);

    int abase[4];
    #pragma unroll
    for (int s = 0; s < 4; s++) {
        int C = 4 * s + g; if (C > 14) C = 14;
        abase[s] = (il >> 2) * IMG1 + (C / 5) * 1024 + (C % 5) * 32;
    }
    int q = il & 3;
    int offq = (q < 2) ? 25 * q : (q == 2 ? 50 : 74);
    int n = il, o = n >> 2, dx = n & 3;
    bool doStCol = ((n & 1) == 0) && (n < 12);
    float vmax = 0.f;
    for (int uu = wid; uu < 25; uu += 4) {
        int p = offq + uu; if (p > 97) p = 97;
        int pb = p / 14, py = p % 14;
        f32x4 acc[2][2];
        #pragma unroll
        for (int H = 0; H < 2; H++)
            #pragma unroll
            for (int yo = 0; yo < 2; yo++) acc[H][yo] = (f32x4){0.f, 0.f, 0.f, 0.f};
        #pragma unroll
        for (int yo = 0; yo < 2; yo++) {
            int y = 2 * py + yo;
            #pragma unroll
            for (int s = 0; s < 4; s++) {
                int addr = abase[s] + y * 32 + 4 * pb;
                union { unsigned long long u[2]; short8 v; } tA;
                tA.u[0] = *(const unsigned long long*)(xs + swz(addr));
                tA.u[1] = *(const unsigned long long*)(xs + swz(addr + 4));
                acc[0][yo] = __builtin_amdgcn_mfma_f32_16x16x32_bf16(tA.v, Bf[0][s], acc[0][yo], 0, 0, 0);
                acc[1][yo] = __builtin_amdgcn_mfma_f32_16x16x32_bf16(tA.v, Bf[1][s], acc[1][yo], 0, 0, 0);
            }
        }
        #pragma unroll
        for (int H = 0; H < 2; H++)
            #pragma unroll
            for (int r = 0; r < 4; r++) {
                float m = fmaxf(acc[H][0][r], acc[H][1][r]);      // pool over y-pair
                float pooled = fmaxf(m, __shfl_xor(m, 1));        // pool over dx-pair
                int cntr = (r < 2) ? 25 : 24;
                if (doStCol && uu < cntr) {
                    int offr = (r < 2) ? 25 * r : (r == 2 ? 50 : 74);
                    int pr = offr + uu, pbr = pr / 14, pyr = pr % 14;
                    float v = fmaxf(pooled * mscale, 0.f);
                    int oc = 3 * H + o, px = 2 * pbr + (dx >> 1);
                    h1[((long)(b0 + g) * 6 + oc) * 224 + pyr * 16 + px] = v;
                    vmax = fmaxf(vmax, v);
                }
            }
    }
    vmax = block_maxN(vmax, red, 4);
    if (tid == 0) atomicMax(slot_out, __float_as_uint(vmax));
}

// ---------------- conv2 MFMA: padded h1 -> [B,16,25], 4 img/block ----------------
__global__ __launch_bounds__(256) void k_conv2(
    const float* __restrict__ h1, const unsigned short* __restrict__ bf2,
    const unsigned* __restrict__ slots, unsigned* __restrict__ slot_out,
    float* __restrict__ h2)
{
    __shared__ unsigned short xs[4 * IMG2];
    __shared__ float red[4];
    int b0 = blockIdx.x * 4, tid = threadIdx.x;
    int lane = tid & 63, wid = tid >> 6;
    int il = lane & 15, g = lane >> 4;
    short8 Bf[2][8];
    #pragma unroll
    for (int H = 0; H < 2; H++)
        #pragma unroll
        for (int s = 0; s < 8; s++)
            Bf[H][s] = *(const short8*)(bf2 + ((H * 8 + s) * 64 + lane) * 8);
    float s1 = get_scale(slots, 1);
    #pragma unroll
    for (int img = 0; img < 4; img++) {
        const float4* src = (const float4*)(h1 + (long)(b0 + img) * 1344);
        for (int i = tid; i < 336; i += 256) {
            float4 v = src[i];
            unsigned pk0 = f2bf(rintf(v.x / s1)) | (f2bf(rintf(v.y / s1)) << 16);
            unsigned pk1 = f2bf(rintf(v.z / s1)) | (f2bf(rintf(v.w / s1)) << 16);
            *(uint2*)&xs[swz(img * IMG2 + 4 * i)] = make_uint2(pk0, pk1);
        }
    }
    __syncthreads();
    float mscale = s1 * get_scale(slots, 6);

    int abase[8];
    #pragma unroll
    for (int s = 0; s < 8; s++) {
        int C = 4 * s + g; if (C > 29) C = 29;
        abase[s] = (il >> 2) * IMG2 + (C / 5) * 224 + (C % 5) * 16;
    }
    int q = il & 3;
    int offq = (q == 0) ? 0 : (6 * q + 1);   // {0,7,13,19}
    int n = il, o = n >> 1;
    bool doStCol = ((n & 1) == 0);
    float vmax = 0.f;
    for (int uu = wid; uu < 7; uu += 4) {
        int p = offq + uu; if (p > 24) p = 24;
        int pb = p / 5, py = p % 5;
        f32x4 acc[2][2];
        #pragma unroll
        for (int H = 0; H < 2; H++)
            #pragma unroll
            for (int yo = 0; yo < 2; yo++) acc[H][yo] = (f32x4){0.f, 0.f, 0.f, 0.f};
        #pragma unroll
        for (int yo = 0; yo < 2; yo++) {
            int y = 2 * py + yo;
            #pragma unroll
            for (int s = 0; s < 8; s++) {
                int addr = abase[s] + y * 16 + 2 * pb;
                union { unsigned u[4]; short8 v; } tA;
                tA.u[0] = *(const unsigned*)(xs + swz(addr));
                tA.u[1] = *(const unsigned*)(xs + swz(addr + 2));
                tA.u[2] = *(const unsigned*)(xs + swz(addr + 4));
                tA.u[3] = *(const unsigned*)(xs + swz(addr + 6));
                acc[0][yo] = __builtin_amdgcn_mfma_f32_16x16x32_bf16(tA.v, Bf[0][s], acc[0][yo], 0, 0, 0);
                acc[1][yo] = __builtin_amdgcn_mfma_f32_16x16x32_bf16(tA.v, Bf[1][s], acc[1][yo], 0, 0, 0);
            }
        }
        #pragma unroll
        for (int H = 0; H < 2; H++)
            #pragma unroll
            for (int r = 0; r < 4; r++) {
                float m = fmaxf(acc[H][0][r], acc[H][1][r]);
                float pooled = fmaxf(m, __shfl_xor(m, 1));
                int cntr = (r == 0) ? 7 : 6;
                if (doStCol && uu < cntr) {
                    int offr = (r == 0) ? 0 : (6 * r + 1);
                    int pr = offr + uu, pbr = pr / 5, pyr = pr % 5;
                    float v = fmaxf(pooled * mscale, 0.f);
                    int oc = 8 * H + o;
                    h2[((long)(b0 + g) * 16 + oc) * 25 + pyr * 5 + pbr] = v;
                    vmax = fmaxf(vmax, v);
                }
            }
    }
    vmax = block_maxN(vmax, red, 4);
    if (tid == 0) atomicMax(slot_out, __float_as_uint(vmax));
}

// ---------------- conv3 MFMA GEMM: [B,400]x[120,400] -> [B,120], 16 img/block, 8 waves ----------------
__global__ __launch_bounds__(512) void k_conv3(
    const float* __restrict__ h2, const unsigned short* __restrict__ bf3,
    const unsigned* __restrict__ slots, unsigned* __restrict__ slot_out,
    float* __restrict__ h3)
{
    __shared__ unsigned short xs[16 * 408];
    __shared__ float red[8];
    int b0 = blockIdx.x * 16, tid = threadIdx.x;
    int lane = tid & 63, wid = tid >> 6;
    int il = lane & 15, g = lane >> 4;
    short8 Bf[13];
    #pragma unroll
    for (int s = 0; s < 13; s++)
        Bf[s] = *(const short8*)(bf3 + ((wid * 13 + s) * 64 + lane) * 8);
    float s2 = get_scale(slots, 2);
    for (int i = tid; i < 3200; i += 512) {
        int img = i / 200, p = i % 200;
        float2 v = *(const float2*)(h2 + (long)(b0 + img) * 400 + 2 * p);
        unsigned pk = f2bf(rintf(v.x / s2)) | (f2bf(rintf(v.y / s2)) << 16);
        *(unsigned*)&xs[img * 408 + 2 * p] = pk;
    }
    __syncthreads();
    float mscale = s2 * get_scale(slots, 7);
    f32x4 acc = (f32x4){0.f, 0.f, 0.f, 0.f};
    #pragma unroll
    for (int s = 0; s < 13; s++) {
        int C = 4 * s + g; if (C > 49) C = 49;
        int addr = il * 408 + 8 * C;
        union { unsigned long long u[2]; short8 v; } tA;
        tA.u[0] = *(const unsigned long long*)(xs + addr);
        tA.u[1] = *(const unsigned long long*)(xs + addr + 4);
        acc = __builtin_amdgcn_mfma_f32_16x16x32_bf16(tA.v, Bf[s], acc, 0, 0, 0);
    }
    float vmax = 0.f;
    int oc = wid * 16 + il;
    if (oc < 120) {
        #pragma unroll
        for (int r = 0; r < 4; r++) {
            float v = fmaxf(acc[r] * mscale, 0.f);
            h3[(long)(b0 + 4 * g + r) * 120 + oc] = v;
            vmax = fmaxf(vmax, v);
        }
    }
    vmax = block_maxN(vmax, red, 8);
    if (tid == 0) atomicMax(slot_out, __float_as_uint(vmax));
}

// ---------------- fc4 MFMA GEMM: [B,120]x[84,120] -> [B,84], 16 img/block, 8 waves ----------------
__global__ __launch_bounds__(512) void k_fc4(
    const float* __restrict__ h3, const unsigned short* __restrict__ bf4,
    const unsigned* __restrict__ slots, unsigned* __restrict__ slot_out,
    float* __restrict__ h4)
{
    __shared__ unsigned short xs[16 * 136];
    __shared__ float red[8];
    int b0 = blockIdx.x * 16, tid = threadIdx.x;
    int lane = tid & 63, wid = tid >> 6;
    int il = lane & 15, g = lane >> 4;
    short8 Bf[4];
    if (wid < 6) {
        #pragma unroll
        for (int s = 0; s < 4; s++)
            Bf[s] = *(const short8*)(bf4 + ((wid * 4 + s) * 64 + lane) * 8);
    }
    float s3 = get_scale(slots, 3);
    for (int i = tid; i < 960; i += 512) {
        int img = i / 60, p = i % 60;
        float2 v = *(const float2*)(h3 + (long)(b0 + img) * 120 + 2 * p);
        unsigned pk = f2bf(rintf(v.x / s3)) | (f2bf(rintf(v.y / s3)) << 16);
        *(unsigned*)&xs[img * 136 + 2 * p] = pk;
    }
    __syncthreads();
    float mscale = s3 * get_scale(slots, 8);
    float vmax = 0.f;
    if (wid < 6) {
        f32x4 acc = (f32x4){0.f, 0.f, 0.f, 0.f};
        #pragma unroll
        for (int s = 0; s < 4; s++) {
            int C = 4 * s + g; if (C > 14) C = 14;
            int addr = il * 136 + 8 * C;
            union { unsigned long long u[2]; short8 v; } tA;
            tA.u[0] = *(const unsigned long long*)(xs + addr);
            tA.u[1] = *(const unsigned long long*)(xs + addr + 4);
            acc = __builtin_amdgcn_mfma_f32_16x16x32_bf16(tA.v, Bf[s], acc, 0, 0, 0);
        }
        int oc = wid * 16 + il;
        if (oc < 84) {
            #pragma unroll
            for (int r = 0; r < 4; r++) {
                float v = fmaxf(acc[r] * mscale, 0.f);
                h4[(long)(b0 + 4 * g + r) * 84 + oc] = v;
                vmax = fmaxf(vmax, v);
            }
        }
    }
    vmax = block_maxN(vmax, red, 8);
    if (tid == 0) atomicMax(slot_out, __float_as_uint(vmax));
}

// ---------------- fc5 MFMA: [B,84]x[10,84] -> out [B,10]; 4 indep waves x 16 img ----------------
__global__ __launch_bounds__(256) void k_fc5(
    const float* __restrict__ h4, const unsigned short* __restrict__ bf5,
    const unsigned* __restrict__ slots, float* __restrict__ out)
{
    __shared__ unsigned short xs[4 * 16 * 104];
    int tid = threadIdx.x;
    int lane = tid & 63, w = tid >> 6;
    int il = lane & 15, g = lane >> 4;
    int b0w = blockIdx.x * 64 + w * 16;
    short8 Bf[3];
    #pragma unroll
    for (int s = 0; s < 3; s++)
        Bf[s] = *(const short8*)(bf5 + ((s * 64) + lane) * 8);
    float s4 = get_scale(slots, 4);
    for (int i = lane; i < 672; i += 64) {
        int img = i / 42, j = i % 42;
        float2 v = *(const float2*)(h4 + (long)(b0w + img) * 84 + 2 * j);
        unsigned pk = f2bf(rintf(v.x / s4)) | (f2bf(rintf(v.y / s4)) << 16);
        *(unsigned*)&xs[w * 1664 + img * 104 + 2 * j] = pk;
    }
    for (int i = lane; i < 96; i += 64) {   // zero pad k=84..95
        int img = i / 6, j = i % 6;
        *(unsigned*)&xs[w * 1664 + img * 104 + 84 + 2 * j] = 0u;
    }
    __syncthreads();
    float mscale = s4 * get_scale(slots, 9);
    f32x4 acc = (f32x4){0.f, 0.f, 0.f, 0.f};
    #pragma unroll
    for (int s = 0; s < 3; s++) {
        int addr = w * 1664 + il * 104 + 32 * s + 8 * g;
        union { unsigned long long u[2]; short8 v; } tA;
        tA.u[0] = *(const unsigned long long*)(xs + addr);
        tA.u[1] = *(const unsigned long long*)(xs + addr + 4);
        acc = __builtin_amdgcn_mfma_f32_16x16x32_bf16(tA.v, Bf[s], acc, 0, 0, 0);
    }
    if (il < 10) {
        #pragma unroll
        for (int r = 0; r < 4; r++)
            out[(long)(b0w + 4 * g + r) * 10 + il] = acc[r] * mscale;
    }
}

extern "C" void kernel_launch(void* const* d_in, const int* in_sizes, int n_in,
                              void* d_out, int out_size, void* d_ws, size_t ws_size,
                              hipStream_t stream) {
    const float* x  = (const float*)d_in[0];
    const float* w1 = (const float*)d_in[1];
    const float* w2 = (const float*)d_in[2];
    const float* w3 = (const float*)d_in[3];
    const float* w4 = (const float*)d_in[4];
    const float* w5 = (const float*)d_in[5];
    float* out = (float*)d_out;
    float* ws = (float*)d_ws;
    unsigned* slots = (unsigned*)d_ws;
    unsigned short* bf1 = (unsigned short*)(ws + OFF_BF1);
    unsigned short* bf2 = (unsigned short*)(ws + OFF_BF2);
    unsigned short* bf3 = (unsigned short*)(ws + OFF_BF3);
    unsigned short* bf4 = (unsigned short*)(ws + OFF_BF4);
    unsigned short* bf5 = (unsigned short*)(ws + OFF_BF5);
    float* h1 = ws + OFF_H1;
    float* h2 = ws + OFF_H2;
    float* h3 = ws + OFF_H3;   // reuses h1's region (dead after conv2)
    float* h4 = ws + OFF_H4;

    hipMemsetAsync(d_ws, 0, 64, stream);   // zero the 16 absmax slots
    k_absmax_all<<<2112, 256, 0, stream>>>((const float4*)x, w1, w2, w3, w4, w5, slots);
    k_bfrag<<<310, 256, 0, stream>>>(w1, w2, w3, w4, w5, slots, bf1, bf2, bf3, bf4, bf5);
    k_conv1<<<1024, 256, 0, stream>>>(x, bf1, slots, slots + 1, h1);
    k_conv2<<<1024, 256, 0, stream>>>(h1, bf2, slots, slots + 2, h2);
    k_conv3<<<256, 512, 0, stream>>>(h2, bf3, slots, slots + 3, h3);
    k_fc4<<<256, 512, 0, stream>>>(h3, bf4, slots, slots + 4, h4);
    k_fc5<<<64, 256, 0, stream>>>(h4, bf5, slots, out);
}